// Round 2
// baseline (3809.520 us; speedup 1.0000x reference)
//
#include <hip/hip_runtime.h>
#include <math.h>

#define N_ROWS 32768
#define K_CODES 8192
#define DIM 512
#define Q_OFF ((size_t)N_ROWS * DIM)   // 16777216 floats of quantized output

#define BM 128
#define BN 128
#define BD 32
#define LDS_STRIDE (BM + 4)            // 132 floats; 132%32=4 -> conflict-free-ish rotation
#define NSPLIT 2
#define KSPLIT (K_CODES / NSPLIT)      // 4096 codes per split
#define MARGIN 2e-3f                   // >> worst-case fp32 accumulation error (~4e-4)

// ---------------------------------------------------------------------------
// Kernel 1: zero histogram counts + compute ||e||^2 per code (one wave/code)
// ---------------------------------------------------------------------------
__global__ __launch_bounds__(256) void vq_esq_init(const float* __restrict__ emb,
                                                   float* __restrict__ esq,
                                                   int* __restrict__ counts) {
    int gid = blockIdx.x * 256 + threadIdx.x;
    if (gid < K_CODES) counts[gid] = 0;
    int code = gid >> 6;
    int lane = gid & 63;
    const float4* p = reinterpret_cast<const float4*>(emb + (size_t)code * DIM);
    float s = 0.f;
#pragma unroll
    for (int k = 0; k < 2; ++k) {
        float4 v = p[lane + 64 * k];
        s += v.x * v.x + v.y * v.y + v.z * v.z + v.w * v.w;
    }
#pragma unroll
    for (int off = 32; off > 0; off >>= 1) s += __shfl_down(s, off);
    if (lane == 0) esq[code] = s;
}

// ---------------------------------------------------------------------------
// Kernel 2: fused distance GEMM + per-row top-2 argmin.
// Tile: BM=128 rows x BN=128 codes, 256 threads, 8x8 register tile.
// Score s = ||e||^2 - 2*x.e  (||x||^2 is constant per row -> argmin invariant).
// Each block handles one row-tile x one half of the codebook (blockIdx.y).
// ---------------------------------------------------------------------------
__global__ __launch_bounds__(256) void vq_argmin(const float* __restrict__ x,
                                                 const float* __restrict__ emb,
                                                 const float* __restrict__ esq,
                                                 float* __restrict__ v1o, float* __restrict__ v2o,
                                                 int* __restrict__ i1o, int* __restrict__ i2o) {
    __shared__ __align__(16) float smem[2 * BD * LDS_STRIDE];
    float (*xs)[LDS_STRIDE] = reinterpret_cast<float (*)[LDS_STRIDE]>(smem);
    float (*es)[LDS_STRIDE] = reinterpret_cast<float (*)[LDS_STRIDE]>(smem + BD * LDS_STRIDE);

    const int tid = threadIdx.x;
    const int ti = tid >> 4;              // 0..15 : rows ti*8 .. ti*8+7
    const int tj = tid & 15;              // 0..15 : cols {tj*4..+3} U {64+tj*4..+3}
    const int row0 = blockIdx.x * BM;
    const int csplit0 = blockIdx.y * KSPLIT;

    const int lrow = tid >> 1;            // 0..127 (tile row for staging loads)
    const int lds4 = (tid & 1) * 16;      // d-offset 0 or 16 (16 floats each)

    float v1[8], v2[8];
    int i1[8], i2[8];
#pragma unroll
    for (int i = 0; i < 8; ++i) { v1[i] = INFINITY; v2[i] = INFINITY; i1[i] = 0; i2[i] = 0; }

    for (int cc = 0; cc < KSPLIT; cc += BN) {
        const int c0 = csplit0 + cc;
        float acc[8][8];
#pragma unroll
        for (int i = 0; i < 8; ++i)
#pragma unroll
            for (int j = 0; j < 8; ++j) acc[i][j] = 0.f;

        for (int d0 = 0; d0 < DIM; d0 += BD) {
            // -------- global loads (16 floats per thread per matrix) --------
            const float4* xp = reinterpret_cast<const float4*>(x + (size_t)(row0 + lrow) * DIM + d0 + lds4);
            float4 xa = xp[0], xb = xp[1], xc = xp[2], xd = xp[3];
            const float4* ep = reinterpret_cast<const float4*>(emb + (size_t)(c0 + lrow) * DIM + d0 + lds4);
            float4 ea = ep[0], eb = ep[1], ec = ep[2], ed = ep[3];

            __syncthreads();   // previous compute done before overwrite
            // -------- transposed LDS stores: [d][row] --------
            xs[lds4 +  0][lrow] = xa.x; xs[lds4 +  1][lrow] = xa.y; xs[lds4 +  2][lrow] = xa.z; xs[lds4 +  3][lrow] = xa.w;
            xs[lds4 +  4][lrow] = xb.x; xs[lds4 +  5][lrow] = xb.y; xs[lds4 +  6][lrow] = xb.z; xs[lds4 +  7][lrow] = xb.w;
            xs[lds4 +  8][lrow] = xc.x; xs[lds4 +  9][lrow] = xc.y; xs[lds4 + 10][lrow] = xc.z; xs[lds4 + 11][lrow] = xc.w;
            xs[lds4 + 12][lrow] = xd.x; xs[lds4 + 13][lrow] = xd.y; xs[lds4 + 14][lrow] = xd.z; xs[lds4 + 15][lrow] = xd.w;
            es[lds4 +  0][lrow] = ea.x; es[lds4 +  1][lrow] = ea.y; es[lds4 +  2][lrow] = ea.z; es[lds4 +  3][lrow] = ea.w;
            es[lds4 +  4][lrow] = eb.x; es[lds4 +  5][lrow] = eb.y; es[lds4 +  6][lrow] = eb.z; es[lds4 +  7][lrow] = eb.w;
            es[lds4 +  8][lrow] = ec.x; es[lds4 +  9][lrow] = ec.y; es[lds4 + 10][lrow] = ec.z; es[lds4 + 11][lrow] = ec.w;
            es[lds4 + 12][lrow] = ed.x; es[lds4 + 13][lrow] = ed.y; es[lds4 + 14][lrow] = ed.z; es[lds4 + 15][lrow] = ed.w;
            __syncthreads();

#pragma unroll 4
            for (int d = 0; d < BD; ++d) {
                float4 xv0 = *reinterpret_cast<const float4*>(&xs[d][ti * 8]);
                float4 xv1 = *reinterpret_cast<const float4*>(&xs[d][ti * 8 + 4]);
                float4 ev0 = *reinterpret_cast<const float4*>(&es[d][tj * 4]);
                float4 ev1 = *reinterpret_cast<const float4*>(&es[d][64 + tj * 4]);
                float xr[8] = {xv0.x, xv0.y, xv0.z, xv0.w, xv1.x, xv1.y, xv1.z, xv1.w};
                float er[8] = {ev0.x, ev0.y, ev0.z, ev0.w, ev1.x, ev1.y, ev1.z, ev1.w};
#pragma unroll
                for (int i = 0; i < 8; ++i)
#pragma unroll
                    for (int j = 0; j < 8; ++j)
                        acc[i][j] = fmaf(xr[i], er[j], acc[i][j]);
            }
        }

        // -------- fold into per-thread top-2 (codes seen in increasing order) ----
#pragma unroll
        for (int j = 0; j < 8; ++j) {
            int c = c0 + ((j < 4) ? (tj * 4 + j) : (64 + tj * 4 + (j - 4)));
            float eq = esq[c];
#pragma unroll
            for (int i = 0; i < 8; ++i) {
                float s = fmaf(-2.f, acc[i][j], eq);
                if (s < v1[i])      { v2[i] = v1[i]; i2[i] = i1[i]; v1[i] = s; i1[i] = c; }
                else if (s < v2[i]) { v2[i] = s; i2[i] = c; }
            }
        }
    }

    // -------- cross-thread top-2 merge (16 threads per row) via LDS --------
    __syncthreads();
    float4* red = reinterpret_cast<float4*>(smem);   // [BM][16] float4 = 32 KiB
#pragma unroll
    for (int i = 0; i < 8; ++i) {
        float4 t;
        t.x = v1[i]; t.y = v2[i];
        t.z = __int_as_float(i1[i]); t.w = __int_as_float(i2[i]);
        red[(ti * 8 + i) * 16 + tj] = t;
    }
    __syncthreads();
    if (tid < BM) {
        float V1 = INFINITY, V2 = INFINITY;
        int I1 = 0x7fffffff, I2 = 0x7fffffff;
        for (int t = 0; t < 16; ++t) {
            float4 e = red[tid * 16 + t];
            float a = e.x; int ia = __float_as_int(e.z);
            float b = e.y; int ib = __float_as_int(e.w);
            if (a < V1 || (a == V1 && ia < I1)) { V2 = V1; I2 = I1; V1 = a; I1 = ia; }
            else if (a < V2 || (a == V2 && ia < I2)) { V2 = a; I2 = ia; }
            if (b < V1 || (b == V1 && ib < I1)) { V2 = V1; I2 = I1; V1 = b; I1 = ib; }
            else if (b < V2 || (b == V2 && ib < I2)) { V2 = b; I2 = ib; }
        }
        size_t o = (size_t)blockIdx.y * N_ROWS + row0 + tid;
        v1o[o] = V1; v2o[o] = V2; i1o[o] = I1; i2o[o] = I2;
    }
}

// ---------------------------------------------------------------------------
// Kernel 3: per-row (one wave): merge splits, fp64 refine near-ties, gather
// embedding row -> out, loss partial, histogram, index write.
// ---------------------------------------------------------------------------
__global__ __launch_bounds__(64) void vq_gather(const float* __restrict__ x,
                                                const float* __restrict__ emb,
                                                const float* __restrict__ v1,
                                                const float* __restrict__ v2,
                                                const int* __restrict__ i1,
                                                const int* __restrict__ i2,
                                                float* __restrict__ out,
                                                int* __restrict__ counts,
                                                float* __restrict__ lossp) {
    const int row = blockIdx.x;
    const int lane = threadIdx.x;

    float V1 = INFINITY, V2 = INFINITY;
    int I1 = 0x7fffffff, I2 = 0x7fffffff;
#pragma unroll
    for (int s = 0; s < NSPLIT; ++s) {
        size_t o = (size_t)s * N_ROWS + row;
        float a = v1[o], b = v2[o];
        int ia = i1[o], ib = i2[o];
        if (a < V1 || (a == V1 && ia < I1)) { V2 = V1; I2 = I1; V1 = a; I1 = ia; }
        else if (a < V2 || (a == V2 && ia < I2)) { V2 = a; I2 = ia; }
        if (b < V1 || (b == V1 && ib < I1)) { V2 = V1; I2 = I1; V1 = b; I1 = ib; }
        else if (b < V2 || (b == V2 && ib < I2)) { V2 = b; I2 = ib; }
    }

    int c = I1;
    if (V2 - V1 < MARGIN && I2 != I1) {
        // fp64 re-evaluation of both candidates (matches fp64 numpy reference
        // to ~1e-13 relative; ties beyond that are measure-zero)
        double d1 = 0.0, d2 = 0.0;
        const float* xr = x + (size_t)row * DIM;
        const float* e1 = emb + (size_t)I1 * DIM;
        const float* e2 = emb + (size_t)I2 * DIM;
        for (int k = lane; k < DIM; k += 64) {
            double xv = (double)xr[k];
            double t1 = xv - (double)e1[k];
            double t2 = xv - (double)e2[k];
            d1 = fma(t1, t1, d1);
            d2 = fma(t2, t2, d2);
        }
#pragma unroll
        for (int off = 32; off > 0; off >>= 1) {
            d1 += __shfl_down(d1, off);
            d2 += __shfl_down(d2, off);
        }
        int sel = (d2 < d1 || (d2 == d1 && I2 < I1)) ? I2 : I1;
        c = __shfl(sel, 0);
    }

    const float4* xr4 = reinterpret_cast<const float4*>(x + (size_t)row * DIM);
    const float4* er4 = reinterpret_cast<const float4*>(emb + (size_t)c * DIM);
    float4* qo = reinterpret_cast<float4*>(out + (size_t)row * DIM);
    float lsum = 0.f;
#pragma unroll
    for (int k = 0; k < 2; ++k) {
        int idx = lane + 64 * k;
        float4 e = er4[idx];
        float4 xv = xr4[idx];
        qo[idx] = e;
        float dx = xv.x - e.x, dy = xv.y - e.y, dz = xv.z - e.z, dw = xv.w - e.w;
        lsum += dx * dx + dy * dy + dz * dz + dw * dw;
    }
#pragma unroll
    for (int off = 32; off > 0; off >>= 1) lsum += __shfl_down(lsum, off);
    if (lane == 0) {
        lossp[row] = lsum;
        atomicAdd(&counts[c], 1);
        out[Q_OFF + 2 + row] = (float)c;   // indices as float (d_out is f32)
    }
}

// ---------------------------------------------------------------------------
// Kernel 4: single block: fp64 loss sum + perplexity, write scalars.
// ---------------------------------------------------------------------------
__global__ __launch_bounds__(256) void vq_finalize(const float* __restrict__ lossp,
                                                   const int* __restrict__ counts,
                                                   float* __restrict__ out) {
    __shared__ double sred[8];
    const int tid = threadIdx.x;
    const int lane = tid & 63, wv = tid >> 6;
    double ls = 0.0, hs = 0.0;
    for (int r = tid; r < N_ROWS; r += 256) ls += (double)lossp[r];
    for (int cidx = tid; cidx < K_CODES; cidx += 256) {
        double p = (double)counts[cidx] * (1.0 / (double)N_ROWS);
        hs += p * log(p + 1e-10);
    }
#pragma unroll
    for (int off = 32; off > 0; off >>= 1) {
        ls += __shfl_down(ls, off);
        hs += __shfl_down(hs, off);
    }
    if (lane == 0) { sred[wv] = ls; sred[4 + wv] = hs; }
    __syncthreads();
    if (tid == 0) {
        double L = sred[0] + sred[1] + sred[2] + sred[3];
        double H = sred[4] + sred[5] + sred[6] + sred[7];
        out[Q_OFF]     = (float)(0.25 * L / (double)Q_OFF);   // commitment loss
        out[Q_OFF + 1] = (float)exp(-H);                      // perplexity
    }
}

// ---------------------------------------------------------------------------
extern "C" void kernel_launch(void* const* d_in, const int* in_sizes, int n_in,
                              void* d_out, int out_size, void* d_ws, size_t ws_size,
                              hipStream_t stream) {
    const float* x   = (const float*)d_in[0];
    const float* emb = (const float*)d_in[1];
    float* out = (float*)d_out;

    // workspace layout (~1.2 MB)
    float* esq    = (float*)d_ws;                 // 8192
    float* v1     = esq + K_CODES;                // NSPLIT*N_ROWS
    float* v2     = v1 + NSPLIT * N_ROWS;
    int*   i1     = (int*)(v2 + NSPLIT * N_ROWS);
    int*   i2     = i1 + NSPLIT * N_ROWS;
    int*   counts = i2 + NSPLIT * N_ROWS;         // 8192
    float* lossp  = (float*)(counts + K_CODES);   // 32768

    vq_esq_init<<<(K_CODES * 64) / 256, 256, 0, stream>>>(emb, esq, counts);
    vq_argmin<<<dim3(N_ROWS / BM, NSPLIT), 256, 0, stream>>>(x, emb, esq, v1, v2, i1, i2);
    vq_gather<<<N_ROWS, 64, 0, stream>>>(x, emb, v1, v2, i1, i2, out, counts, lossp);
    vq_finalize<<<1, 256, 0, stream>>>(lossp, counts, out);
}

// Round 3
// 2853.635 us; speedup vs baseline: 1.3350x; 1.3350x over previous
//
#include <hip/hip_runtime.h>
#include <math.h>

#define N_ROWS 32768
#define K_CODES 8192
#define DIM 512
#define Q_OFF ((size_t)N_ROWS * DIM)   // 16777216 floats of quantized output

#define NSPLIT 2                        // code-dim split across blockIdx.y
#define KSPL (K_CODES / NSPLIT)         // 4096 codes per split
#define NSPLIT2 (NSPLIT * 2)            // x2: wc wave halves also write partials
#define MARGIN 1e-2f                    // >> 3-pass bf16 emulation error (~1.5e-3 max)

typedef short bf16x8 __attribute__((ext_vector_type(8)));
typedef float f32x4 __attribute__((ext_vector_type(4)));

// ---------------------------------------------------------------------------
// f32 -> packed (bf16_hi | bf16_lo) in one u32.  hi = trunc16(x) in high half,
// lo = trunc16(x - hi) in low half.  x - hi is exact in f32.
// ---------------------------------------------------------------------------
__device__ __forceinline__ unsigned int packf(unsigned int u) {
    unsigned int hi = u & 0xFFFF0000u;
    float lf = __uint_as_float(u) - __uint_as_float(hi);
    return hi | (__float_as_uint(lf) >> 16);
}

__global__ __launch_bounds__(256) void vq_pack(const uint4* __restrict__ src,
                                               uint4* __restrict__ dst, int n4) {
    int i = blockIdx.x * 256 + threadIdx.x;
    if (i >= n4) return;
    uint4 v = src[i];
    v.x = packf(v.x); v.y = packf(v.y); v.z = packf(v.z); v.w = packf(v.w);
    dst[i] = v;
}

// ---------------------------------------------------------------------------
// Kernel 1: zero histogram counts + compute ||e||^2 per code (one wave/code)
// ---------------------------------------------------------------------------
__global__ __launch_bounds__(256) void vq_esq_init(const float* __restrict__ emb,
                                                   float* __restrict__ esq,
                                                   int* __restrict__ counts) {
    int gid = blockIdx.x * 256 + threadIdx.x;
    if (gid < K_CODES) counts[gid] = 0;
    int code = gid >> 6;
    int lane = gid & 63;
    const float4* p = reinterpret_cast<const float4*>(emb + (size_t)code * DIM);
    float s = 0.f;
#pragma unroll
    for (int k = 0; k < 2; ++k) {
        float4 v = p[lane + 64 * k];
        s += v.x * v.x + v.y * v.y + v.z * v.z + v.w * v.w;
    }
#pragma unroll
    for (int off = 32; off > 0; off >>= 1) s += __shfl_down(s, off);
    if (lane == 0) esq[code] = s;
}

// ---------------------------------------------------------------------------
// MFMA argmin kernel.  Block tile 128 rows x 128 codes, 4 waves (2x2), each
// wave 64x64 via 4x4 fragments of mfma_f32_16x16x32_bf16, 3 hi/lo passes.
// LDS tiles hold packed u32 (hi|lo), XOR-swizzled 16B slots.
// Score s = ||e||^2 - 2*x.e ; per-lane running top-2 -> shfl_xor tree at end.
// ---------------------------------------------------------------------------
template<bool PKX, bool PKE>
__device__ __forceinline__ void stage_load(const unsigned int* __restrict__ xsrc,
                                           const unsigned int* __restrict__ esrc,
                                           int row0, int c0, int srow, int scol, int ks,
                                           uint4 (&ra)[4], uint4 (&rb)[4]) {
    const unsigned int* ap = xsrc + (size_t)(row0 + srow) * DIM + ks * 32 + scol;
    const unsigned int* bp = esrc + (size_t)(c0 + srow) * DIM + ks * 32 + scol;
#pragma unroll
    for (int m = 0; m < 4; ++m) {
        ra[m] = *reinterpret_cast<const uint4*>(ap + m * 4);
        rb[m] = *reinterpret_cast<const uint4*>(bp + m * 4);
    }
    if constexpr (!PKX) {
#pragma unroll
        for (int m = 0; m < 4; ++m) {
            ra[m].x = packf(ra[m].x); ra[m].y = packf(ra[m].y);
            ra[m].z = packf(ra[m].z); ra[m].w = packf(ra[m].w);
        }
    }
    if constexpr (!PKE) {
#pragma unroll
        for (int m = 0; m < 4; ++m) {
            rb[m].x = packf(rb[m].x); rb[m].y = packf(rb[m].y);
            rb[m].z = packf(rb[m].z); rb[m].w = packf(rb[m].w);
        }
    }
}

// Build hi/lo bf16x8 fragments for one 16-vector of the LDS tile.
// row: tile row 0..127, kg = lane>>4 selects k-group (8 consecutive k).
__device__ __forceinline__ void frag_from_lds(const unsigned int* s, int row, int kg,
                                              bf16x8& hi, bf16x8& lo) {
    int msk = row & 7;
    int base = row * 32;
    uint4 q0 = *reinterpret_cast<const uint4*>(s + base + ((((kg << 1) | 0) ^ msk) << 2));
    uint4 q1 = *reinterpret_cast<const uint4*>(s + base + ((((kg << 1) | 1) ^ msk) << 2));
    union { unsigned int u[4]; bf16x8 v; } H, L;
    H.u[0] = __builtin_amdgcn_perm(q0.y, q0.x, 0x07060302u);
    H.u[1] = __builtin_amdgcn_perm(q0.w, q0.z, 0x07060302u);
    H.u[2] = __builtin_amdgcn_perm(q1.y, q1.x, 0x07060302u);
    H.u[3] = __builtin_amdgcn_perm(q1.w, q1.z, 0x07060302u);
    L.u[0] = __builtin_amdgcn_perm(q0.y, q0.x, 0x05040100u);
    L.u[1] = __builtin_amdgcn_perm(q0.w, q0.z, 0x05040100u);
    L.u[2] = __builtin_amdgcn_perm(q1.y, q1.x, 0x05040100u);
    L.u[3] = __builtin_amdgcn_perm(q1.w, q1.z, 0x05040100u);
    hi = H.v; lo = L.v;
}

template<bool PKX, bool PKE>
__global__ __launch_bounds__(256, 2) void vq_argmin_mfma(
        const unsigned int* __restrict__ xsrc,
        const unsigned int* __restrict__ esrc,
        const float* __restrict__ esq,
        float* __restrict__ v1o, float* __restrict__ v2o,
        unsigned int* __restrict__ io) {
    __shared__ __align__(16) unsigned int as[128 * 32];   // 16 KiB
    __shared__ __align__(16) unsigned int bs[128 * 32];   // 16 KiB

    const int tid = threadIdx.x;
    const int lane = tid & 63;
    const int wid = tid >> 6;
    const int wr = wid >> 1;              // wave row half (0..1)
    const int wc = wid & 1;               // wave col half (0..1)
    const int row0 = blockIdx.x * 128;
    const int c00 = blockIdx.y * KSPL;

    const int srow = tid >> 1;            // staging row 0..127
    const int scol = (tid & 1) * 16;      // staging u32 col base

    const int lr = lane & 15;             // fragment vector index
    const int kg = lane >> 4;             // k-group

    float rv1[16], rv2[16];
    unsigned int ridx[16];
#pragma unroll
    for (int t = 0; t < 16; ++t) { rv1[t] = INFINITY; rv2[t] = INFINITY; ridx[t] = 0; }

    uint4 ra[4], rb[4];

    for (int cc = 0; cc < KSPL; cc += 128) {
        f32x4 acc[4][4];
#pragma unroll
        for (int i = 0; i < 4; ++i)
#pragma unroll
            for (int j = 0; j < 4; ++j) acc[i][j] = (f32x4)(0.f);

        stage_load<PKX, PKE>(xsrc, esrc, row0, c00 + cc, srow, scol, 0, ra, rb);

        for (int ks = 0; ks < 16; ++ks) {
            __syncthreads();
#pragma unroll
            for (int m = 0; m < 4; ++m) {
                int slot = (tid & 1) * 4 + m;
                int sw = srow * 32 + ((slot ^ (srow & 7)) << 2);
                *reinterpret_cast<uint4*>(&as[sw]) = ra[m];
                *reinterpret_cast<uint4*>(&bs[sw]) = rb[m];
            }
            __syncthreads();
            if (ks < 15)
                stage_load<PKX, PKE>(xsrc, esrc, row0, c00 + cc, srow, scol, ks + 1, ra, rb);

            bf16x8 ah[4], al[4];
#pragma unroll
            for (int i = 0; i < 4; ++i)
                frag_from_lds(as, wr * 64 + i * 16 + lr, kg, ah[i], al[i]);
#pragma unroll
            for (int j = 0; j < 4; ++j) {
                bf16x8 bh, bl;
                frag_from_lds(bs, wc * 64 + j * 16 + lr, kg, bh, bl);
#pragma unroll
                for (int i = 0; i < 4; ++i) {
                    acc[i][j] = __builtin_amdgcn_mfma_f32_16x16x32_bf16(ah[i], bh, acc[i][j], 0, 0, 0);
                    acc[i][j] = __builtin_amdgcn_mfma_f32_16x16x32_bf16(ah[i], bl, acc[i][j], 0, 0, 0);
                    acc[i][j] = __builtin_amdgcn_mfma_f32_16x16x32_bf16(al[i], bh, acc[i][j], 0, 0, 0);
                }
            }
        }

        // fold tile into per-lane running top-2 (codes ascending per lane)
#pragma unroll
        for (int j = 0; j < 4; ++j) {
            int cg = c00 + cc + wc * 64 + j * 16 + lr;
            float eq = esq[cg];
#pragma unroll
            for (int i = 0; i < 4; ++i) {
#pragma unroll
                for (int r = 0; r < 4; ++r) {
                    float s = fmaf(-2.f, acc[i][j][r], eq);
                    int t = i * 4 + r;
                    if (s < rv1[t]) {
                        rv2[t] = rv1[t]; ridx[t] = (ridx[t] << 16) | (unsigned int)cg; rv1[t] = s;
                    } else if (s < rv2[t]) {
                        rv2[t] = s; ridx[t] = (ridx[t] & 0xFFFFu) | ((unsigned int)cg << 16);
                    }
                }
            }
        }
    }

    // cross-lane top-2 merge within each 16-lane group (same rows, disjoint cols)
#pragma unroll
    for (int m = 1; m <= 8; m <<= 1) {
#pragma unroll
        for (int t = 0; t < 16; ++t) {
            float bv1 = __shfl_xor(rv1[t], m);
            float bv2 = __shfl_xor(rv2[t], m);
            unsigned int ox = (unsigned int)__shfl_xor((int)ridx[t], m);
            unsigned int ai1 = ridx[t] & 0xFFFFu, ai2 = ridx[t] >> 16;
            unsigned int bi1 = ox & 0xFFFFu, bi2 = ox >> 16;
            float av1 = rv1[t], av2 = rv2[t];
            bool bf = (bv1 < av1) || (bv1 == av1 && bi1 < ai1);
            float n1v = bf ? bv1 : av1; unsigned int n1i = bf ? bi1 : ai1;
            float w1v = bf ? av1 : bv1; unsigned int w1i = bf ? ai1 : bi1;
            bool cf = (bv2 < av2) || (bv2 == av2 && bi2 < ai2);
            float c2v = cf ? bv2 : av2; unsigned int c2i = cf ? bi2 : ai2;
            bool df = (c2v < w1v) || (c2v == w1v && c2i < w1i);
            float n2v = df ? c2v : w1v; unsigned int n2i = df ? c2i : w1i;
            rv1[t] = n1v; rv2[t] = n2v; ridx[t] = n1i | (n2i << 16);
        }
    }

    if ((lane & 15) == 0) {
        int g = lane >> 4;
#pragma unroll
        for (int t = 0; t < 16; ++t) {
            int rl = (t >> 2) * 16 + g * 4 + (t & 3) + wr * 64;
            size_t o = (size_t)(blockIdx.y * 2 + wc) * N_ROWS + row0 + rl;
            v1o[o] = rv1[t]; v2o[o] = rv2[t]; io[o] = ridx[t];
        }
    }
}

// ---------------------------------------------------------------------------
// Kernel 3: per-row (one wave): merge partials, fp64 refine near-ties, gather
// embedding row -> out, loss partial, histogram, index write.
// ---------------------------------------------------------------------------
__global__ __launch_bounds__(64) void vq_gather(const float* __restrict__ x,
                                                const float* __restrict__ emb,
                                                const float* __restrict__ v1,
                                                const float* __restrict__ v2,
                                                const unsigned int* __restrict__ io,
                                                float* __restrict__ out,
                                                int* __restrict__ counts,
                                                float* __restrict__ lossp) {
    const int row = blockIdx.x;
    const int lane = threadIdx.x;

    float V1 = INFINITY, V2 = INFINITY;
    unsigned int I1 = 0xFFFFu, I2 = 0xFFFFu;
#pragma unroll
    for (int s2 = 0; s2 < NSPLIT2; ++s2) {
        size_t o = (size_t)s2 * N_ROWS + row;
        float bv1 = v1[o], bv2 = v2[o];
        unsigned int ox = io[o];
        unsigned int bi1 = ox & 0xFFFFu, bi2 = ox >> 16;
        bool bf = (bv1 < V1) || (bv1 == V1 && bi1 < I1);
        float n1v = bf ? bv1 : V1; unsigned int n1i = bf ? bi1 : I1;
        float w1v = bf ? V1 : bv1; unsigned int w1i = bf ? I1 : bi1;
        bool cf = (bv2 < V2) || (bv2 == V2 && bi2 < I2);
        float c2v = cf ? bv2 : V2; unsigned int c2i = cf ? bi2 : I2;
        bool df = (c2v < w1v) || (c2v == w1v && c2i < w1i);
        V1 = n1v; I1 = n1i;
        V2 = df ? c2v : w1v; I2 = df ? c2i : w1i;
    }

    int c = (int)I1;
    if (V2 - V1 < MARGIN && I2 != I1) {
        // fp64 re-evaluation of both candidates
        double d1 = 0.0, d2 = 0.0;
        const float* xr = x + (size_t)row * DIM;
        const float* e1 = emb + (size_t)I1 * DIM;
        const float* e2 = emb + (size_t)I2 * DIM;
        for (int k = lane; k < DIM; k += 64) {
            double xv = (double)xr[k];
            double t1 = xv - (double)e1[k];
            double t2 = xv - (double)e2[k];
            d1 = fma(t1, t1, d1);
            d2 = fma(t2, t2, d2);
        }
#pragma unroll
        for (int off = 32; off > 0; off >>= 1) {
            d1 += __shfl_down(d1, off);
            d2 += __shfl_down(d2, off);
        }
        int sel = (d2 < d1 || (d2 == d1 && I2 < I1)) ? (int)I2 : (int)I1;
        c = __shfl(sel, 0);
    }

    const float4* xr4 = reinterpret_cast<const float4*>(x + (size_t)row * DIM);
    const float4* er4 = reinterpret_cast<const float4*>(emb + (size_t)c * DIM);
    float4* qo = reinterpret_cast<float4*>(out + (size_t)row * DIM);
    float lsum = 0.f;
#pragma unroll
    for (int k = 0; k < 2; ++k) {
        int idx = lane + 64 * k;
        float4 e = er4[idx];
        float4 xv = xr4[idx];
        qo[idx] = e;
        float dx = xv.x - e.x, dy = xv.y - e.y, dz = xv.z - e.z, dw = xv.w - e.w;
        lsum += dx * dx + dy * dy + dz * dz + dw * dw;
    }
#pragma unroll
    for (int off = 32; off > 0; off >>= 1) lsum += __shfl_down(lsum, off);
    if (lane == 0) {
        lossp[row] = lsum;
        atomicAdd(&counts[c], 1);
        out[Q_OFF + 2 + row] = (float)c;   // indices as float (d_out is f32)
    }
}

// ---------------------------------------------------------------------------
// Kernel 4: single block: fp64 loss sum + perplexity, write scalars.
// ---------------------------------------------------------------------------
__global__ __launch_bounds__(256) void vq_finalize(const float* __restrict__ lossp,
                                                   const int* __restrict__ counts,
                                                   float* __restrict__ out) {
    __shared__ double sred[8];
    const int tid = threadIdx.x;
    const int lane = tid & 63, wv = tid >> 6;
    double ls = 0.0, hs = 0.0;
    for (int r = tid; r < N_ROWS; r += 256) ls += (double)lossp[r];
    for (int cidx = tid; cidx < K_CODES; cidx += 256) {
        double p = (double)counts[cidx] * (1.0 / (double)N_ROWS);
        hs += p * log(p + 1e-10);
    }
#pragma unroll
    for (int off = 32; off > 0; off >>= 1) {
        ls += __shfl_down(ls, off);
        hs += __shfl_down(hs, off);
    }
    if (lane == 0) { sred[wv] = ls; sred[4 + wv] = hs; }
    __syncthreads();
    if (tid == 0) {
        double L = sred[0] + sred[1] + sred[2] + sred[3];
        double H = sred[4] + sred[5] + sred[6] + sred[7];
        out[Q_OFF]     = (float)(0.25 * L / (double)Q_OFF);   // commitment loss
        out[Q_OFF + 1] = (float)exp(-H);                      // perplexity
    }
}

// ---------------------------------------------------------------------------
extern "C" void kernel_launch(void* const* d_in, const int* in_sizes, int n_in,
                              void* d_out, int out_size, void* d_ws, size_t ws_size,
                              hipStream_t stream) {
    const float* x   = (const float*)d_in[0];
    const float* emb = (const float*)d_in[1];
    float* out = (float*)d_out;

    // workspace layout (u32 words)
    unsigned int* w = (unsigned int*)d_ws;
    float* esq          = (float*)(w);                       // 8192
    int*   counts       = (int*)(w + 8192);                  // 8192
    float* lossp        = (float*)(w + 16384);               // 32768
    float* v1           = (float*)(w + 49152);               // 4*32768
    float* v2           = (float*)(w + 180224);              // 4*32768
    unsigned int* io    = (unsigned int*)(w + 311296);       // 4*32768
    unsigned int* e_pk  = (unsigned int*)(w + 442368);       // 8192*512
    unsigned int* x_pk  = (unsigned int*)(w + 4636672);      // 32768*512

    const size_t need_e = (size_t)(442368 + 4194304) * 4;               // ~18.5 MB
    const size_t need_x = (size_t)(442368 + 4194304 + 16777216) * 4;    // ~85.7 MB
    const bool pke = ws_size >= need_e;
    const bool pkx = ws_size >= need_x;

    vq_esq_init<<<(K_CODES * 64) / 256, 256, 0, stream>>>(emb, esq, counts);
    if (pke)
        vq_pack<<<(K_CODES * DIM / 4) / 256, 256, 0, stream>>>(
            (const uint4*)emb, (uint4*)e_pk, K_CODES * DIM / 4);
    if (pkx)
        vq_pack<<<(N_ROWS * DIM / 4) / 256, 256, 0, stream>>>(
            (const uint4*)x, (uint4*)x_pk, N_ROWS * DIM / 4);

    dim3 grid(N_ROWS / 128, NSPLIT);
    if (pkx)
        vq_argmin_mfma<true, true><<<grid, 256, 0, stream>>>(
            x_pk, e_pk, esq, v1, v2, io);
    else if (pke)
        vq_argmin_mfma<false, true><<<grid, 256, 0, stream>>>(
            (const unsigned int*)x, e_pk, esq, v1, v2, io);
    else
        vq_argmin_mfma<false, false><<<grid, 256, 0, stream>>>(
            (const unsigned int*)x, (const unsigned int*)emb, esq, v1, v2, io);

    vq_gather<<<N_ROWS, 64, 0, stream>>>(x, emb, v1, v2, io, out, counts, lossp);
    vq_finalize<<<1, 256, 0, stream>>>(lossp, counts, out);
}

// Round 4
// 641.050 us; speedup vs baseline: 5.9426x; 4.4515x over previous
//
#include <hip/hip_runtime.h>
#include <math.h>

#define N_ROWS 32768
#define K_CODES 8192
#define DIM 512
#define Q_OFF ((size_t)N_ROWS * DIM)   // 16777216 floats of quantized output

#define NSPLIT 2                        // codebook split across blockIdx.y
#define KSPL (K_CODES / NSPLIT)         // 4096 codes per block
#define NPOOL (NSPLIT * 2)              // 4 disjoint 2048-code pools per row
#define MARGIN 0.05f                    // >> f16 2-term score error (~3e-3 max)

typedef _Float16 half8 __attribute__((ext_vector_type(8)));
typedef float f32x4 __attribute__((ext_vector_type(4)));

#define GLOAD_LDS(src, dst)                                                        \
  __builtin_amdgcn_global_load_lds(                                                \
      (const __attribute__((address_space(1))) void*)(src),                        \
      (__attribute__((address_space(3))) void*)(dst), 16, 0, 0)

// ---------------------------------------------------------------------------
// Pack kernels: x -> (x_hi, x_lo) f16 planes (split exact to ~2^-23),
//               e -> single f16 plane.
// ---------------------------------------------------------------------------
__global__ __launch_bounds__(256) void vq_pack_x(const float4* __restrict__ src,
                                                 half8* __restrict__ xh,
                                                 half8* __restrict__ xl, int n8) {
    int i = blockIdx.x * 256 + threadIdx.x;
    if (i >= n8) return;
    float4 a = src[i * 2], b = src[i * 2 + 1];
    float v[8] = {a.x, a.y, a.z, a.w, b.x, b.y, b.z, b.w};
    half8 h, l;
#pragma unroll
    for (int k = 0; k < 8; ++k) {
        _Float16 hh = (_Float16)v[k];
        h[k] = hh;
        l[k] = (_Float16)(v[k] - (float)hh);
    }
    xh[i] = h; xl[i] = l;
}

__global__ __launch_bounds__(256) void vq_pack_e(const float4* __restrict__ src,
                                                 half8* __restrict__ ehp, int n8) {
    int i = blockIdx.x * 256 + threadIdx.x;
    if (i >= n8) return;
    float4 a = src[i * 2], b = src[i * 2 + 1];
    float v[8] = {a.x, a.y, a.z, a.w, b.x, b.y, b.z, b.w};
    half8 h;
#pragma unroll
    for (int k = 0; k < 8; ++k) h[k] = (_Float16)v[k];
    ehp[i] = h;
}

// ---------------------------------------------------------------------------
// Kernel: zero histogram counts + compute ||e||^2 per code (f32, exact-ish)
// ---------------------------------------------------------------------------
__global__ __launch_bounds__(256) void vq_esq_init(const float* __restrict__ emb,
                                                   float* __restrict__ esq,
                                                   int* __restrict__ counts) {
    int gid = blockIdx.x * 256 + threadIdx.x;
    if (gid < K_CODES) counts[gid] = 0;
    int code = gid >> 6;
    int lane = gid & 63;
    const float4* p = reinterpret_cast<const float4*>(emb + (size_t)code * DIM);
    float s = 0.f;
#pragma unroll
    for (int k = 0; k < 2; ++k) {
        float4 v = p[lane + 64 * k];
        s += v.x * v.x + v.y * v.y + v.z * v.z + v.w * v.w;
    }
#pragma unroll
    for (int off = 32; off > 0; off >>= 1) s += __shfl_down(s, off);
    if (lane == 0) esq[code] = s;
}

// ---------------------------------------------------------------------------
// MFMA argmin.  Block tile 128 rows x 256 codes, 4 waves (wr 2 x wc 2), each
// wave 64x128 via 4x8 fragments of mfma_f32_16x16x32_f16, 2 passes
// (x_hi*e + x_lo*e).  LDS: double-buffered {A_hi 8K, A_lo 8K, B 16K} f16
// planes, XOR-swizzled 16B slots (swizzle on global source + on read; linear
// global_load_lds dest).  One barrier per K-step (stage next buf, compute
// current, barrier drains vmcnt+lgkm).
// Score s = ||e||^2 - 2*x.e ; per-lane running top-2 -> shfl_xor tree.
// ---------------------------------------------------------------------------
__device__ __forceinline__ half8 frag16(const _Float16* t, int row, int kg) {
    return *reinterpret_cast<const half8*>(t + row * 32 + ((kg ^ (row & 3)) << 3));
}

template<bool PK>
__global__ __launch_bounds__(256, 2) void vq_argmin_f16(
        const _Float16* __restrict__ xh, const _Float16* __restrict__ xl,
        const _Float16* __restrict__ eh,
        const float* __restrict__ xf, const float* __restrict__ ef,
        const float* __restrict__ esq,
        float* __restrict__ v1o, float* __restrict__ v2o,
        unsigned int* __restrict__ io) {
    __shared__ __align__(16) _Float16 sbuf[2][16384];   // per buf: A_hi 4096 | A_lo 4096 | B 8192 halves

    const int tid = threadIdx.x;
    const int lane = tid & 63;
    const int wid = tid >> 6;
    const int wr = wid >> 1, wc = wid & 1;
    const int lr = lane & 15, kg = lane >> 4;
    const int row0 = blockIdx.x * 128;
    const int csplit0 = blockIdx.y * KSPL;

    // per-lane staging offsets (PK path): linear LDS dest, inverse-swizzled src
    int offA[2], offB[4], dstA[2], dstB[4];
#pragma unroll
    for (int c = 0; c < 2; ++c) {
        int rA = wid * 32 + c * 16 + (lane >> 2);
        int sxA = (lane & 3) ^ (rA & 3);
        offA[c] = rA * DIM + sxA * 8;
        dstA[c] = (wid * 32 + c * 16) * 32;
    }
#pragma unroll
    for (int c = 0; c < 4; ++c) {
        int rB = wid * 64 + c * 16 + (lane >> 2);
        int sxB = (lane & 3) ^ (rB & 3);
        offB[c] = rB * DIM + sxB * 8;
        dstB[c] = (wid * 64 + c * 16) * 32;
    }

    auto stage = [&](int b, int tcc, int tks) {
        if constexpr (PK) {
            const _Float16* xh0 = xh + (size_t)row0 * DIM + tks * 32;
            const _Float16* xl0 = xl + (size_t)row0 * DIM + tks * 32;
            const _Float16* eh0 = eh + (size_t)(csplit0 + tcc * 256) * DIM + tks * 32;
            _Float16* base = &sbuf[b][0];
#pragma unroll
            for (int c = 0; c < 2; ++c) {
                GLOAD_LDS(xh0 + offA[c], base + dstA[c]);
                GLOAD_LDS(xl0 + offA[c], base + 4096 + dstA[c]);
            }
#pragma unroll
            for (int c = 0; c < 4; ++c)
                GLOAD_LDS(eh0 + offB[c], base + 8192 + dstB[c]);
        } else {
            // reg-staging fallback: load f32, convert, ds_write swizzled
            {
                const int r = tid >> 1;
                const int k0 = (tid & 1) * 16;
                const float4* xp = reinterpret_cast<const float4*>(
                    xf + (size_t)(row0 + r) * DIM + tks * 32 + k0);
                float4 f0 = xp[0], f1 = xp[1], f2 = xp[2], f3 = xp[3];
                float v[16] = {f0.x, f0.y, f0.z, f0.w, f1.x, f1.y, f1.z, f1.w,
                               f2.x, f2.y, f2.z, f2.w, f3.x, f3.y, f3.z, f3.w};
                half8 h0, h1, l0, l1;
#pragma unroll
                for (int k = 0; k < 8; ++k) {
                    _Float16 a = (_Float16)v[k];
                    h0[k] = a; l0[k] = (_Float16)(v[k] - (float)a);
                    _Float16 bb = (_Float16)v[8 + k];
                    h1[k] = bb; l1[k] = (_Float16)(v[8 + k] - (float)bb);
                }
                int s0 = (k0 >> 3) ^ (r & 3);
                int s1 = ((k0 >> 3) + 1) ^ (r & 3);
                _Float16* Ah = &sbuf[b][0];
                _Float16* Al = &sbuf[b][4096];
                *reinterpret_cast<half8*>(Ah + r * 32 + s0 * 8) = h0;
                *reinterpret_cast<half8*>(Ah + r * 32 + s1 * 8) = h1;
                *reinterpret_cast<half8*>(Al + r * 32 + s0 * 8) = l0;
                *reinterpret_cast<half8*>(Al + r * 32 + s1 * 8) = l1;
            }
            {
                const int r = tid;
                const float4* ep = reinterpret_cast<const float4*>(
                    ef + (size_t)(csplit0 + tcc * 256 + r) * DIM + tks * 32);
                float4 g[8];
#pragma unroll
                for (int q = 0; q < 8; ++q) g[q] = ep[q];
                _Float16* Be = &sbuf[b][8192];
#pragma unroll
                for (int q = 0; q < 4; ++q) {
                    half8 h;
                    h[0] = (_Float16)g[q * 2].x; h[1] = (_Float16)g[q * 2].y;
                    h[2] = (_Float16)g[q * 2].z; h[3] = (_Float16)g[q * 2].w;
                    h[4] = (_Float16)g[q * 2 + 1].x; h[5] = (_Float16)g[q * 2 + 1].y;
                    h[6] = (_Float16)g[q * 2 + 1].z; h[7] = (_Float16)g[q * 2 + 1].w;
                    *reinterpret_cast<half8*>(Be + r * 32 + ((q ^ (r & 3)) << 3)) = h;
                }
            }
        }
    };

    float rv1[16], rv2[16];
    unsigned int ridx[16];
#pragma unroll
    for (int t = 0; t < 16; ++t) { rv1[t] = INFINITY; rv2[t] = INFINITY; ridx[t] = 0; }

    stage(0, 0, 0);
    __syncthreads();
    int cur = 0;
    const int NCC = KSPL / 256;          // 16 cc-tiles
    for (int cc = 0; cc < NCC; ++cc) {
        f32x4 acc[4][8];
#pragma unroll
        for (int i = 0; i < 4; ++i)
#pragma unroll
            for (int j = 0; j < 8; ++j) acc[i][j] = (f32x4)(0.f);

        for (int ks = 0; ks < 16; ++ks) {
            int s = cc * 16 + ks;
            if (s < NCC * 16 - 1) stage(cur ^ 1, (s + 1) >> 4, (s + 1) & 15);

            const _Float16* Ah = &sbuf[cur][0];
            const _Float16* Al = &sbuf[cur][4096];
            const _Float16* Be = &sbuf[cur][8192];
            half8 ah[4], al[4];
#pragma unroll
            for (int i = 0; i < 4; ++i) {
                int rw = wr * 64 + i * 16 + lr;
                ah[i] = frag16(Ah, rw, kg);
                al[i] = frag16(Al, rw, kg);
            }
#pragma unroll
            for (int j = 0; j < 8; ++j) {
                half8 be = frag16(Be, wc * 128 + j * 16 + lr, kg);
#pragma unroll
                for (int i = 0; i < 4; ++i) {
                    acc[i][j] = __builtin_amdgcn_mfma_f32_16x16x32_f16(ah[i], be, acc[i][j], 0, 0, 0);
                    acc[i][j] = __builtin_amdgcn_mfma_f32_16x16x32_f16(al[i], be, acc[i][j], 0, 0, 0);
                }
            }
            __syncthreads();
            cur ^= 1;
        }

        // fold tile into per-lane running top-2
#pragma unroll
        for (int j = 0; j < 8; ++j) {
            int cg = csplit0 + cc * 256 + wc * 128 + j * 16 + lr;
            float eq = esq[cg];
#pragma unroll
            for (int i = 0; i < 4; ++i) {
#pragma unroll
                for (int r = 0; r < 4; ++r) {
                    float s = fmaf(-2.f, acc[i][j][r], eq);
                    int t = i * 4 + r;
                    if (s < rv1[t]) {
                        rv2[t] = rv1[t]; ridx[t] = (ridx[t] << 16) | (unsigned int)cg; rv1[t] = s;
                    } else if (s < rv2[t]) {
                        rv2[t] = s; ridx[t] = (ridx[t] & 0xFFFFu) | ((unsigned int)cg << 16);
                    }
                }
            }
        }
    }

    // cross-lane top-2 merge within each 16-lane group (same rows, disjoint cols)
#pragma unroll
    for (int m = 1; m <= 8; m <<= 1) {
#pragma unroll
        for (int t = 0; t < 16; ++t) {
            float bv1 = __shfl_xor(rv1[t], m);
            float bv2 = __shfl_xor(rv2[t], m);
            unsigned int ox = (unsigned int)__shfl_xor((int)ridx[t], m);
            unsigned int ai1 = ridx[t] & 0xFFFFu, ai2 = ridx[t] >> 16;
            unsigned int bi1 = ox & 0xFFFFu, bi2 = ox >> 16;
            float av1 = rv1[t], av2 = rv2[t];
            bool bf = (bv1 < av1) || (bv1 == av1 && bi1 < ai1);
            float n1v = bf ? bv1 : av1; unsigned int n1i = bf ? bi1 : ai1;
            float w1v = bf ? av1 : bv1; unsigned int w1i = bf ? ai1 : bi1;
            bool cf = (bv2 < av2) || (bv2 == av2 && bi2 < ai2);
            float c2v = cf ? bv2 : av2; unsigned int c2i = cf ? bi2 : ai2;
            bool df = (c2v < w1v) || (c2v == w1v && c2i < w1i);
            float n2v = df ? c2v : w1v; unsigned int n2i = df ? c2i : w1i;
            rv1[t] = n1v; rv2[t] = n2v; ridx[t] = n1i | (n2i << 16);
        }
    }

    if (lr == 0) {
        int g = kg;
#pragma unroll
        for (int t = 0; t < 16; ++t) {
            int rl = wr * 64 + (t >> 2) * 16 + g * 4 + (t & 3);
            size_t o = (size_t)(blockIdx.y * 2 + wc) * N_ROWS + row0 + rl;
            v1o[o] = rv1[t]; v2o[o] = rv2[t]; io[o] = ridx[t];
        }
    }
}

// ---------------------------------------------------------------------------
// Per-row (one wave): merge 4 pool top-2s; if global gap < MARGIN, fp64
// re-score all 8 candidates; gather embedding row, loss partial, histogram.
// ---------------------------------------------------------------------------
__global__ __launch_bounds__(64) void vq_gather(const float* __restrict__ x,
                                                const float* __restrict__ emb,
                                                const float* __restrict__ v1,
                                                const float* __restrict__ v2,
                                                const unsigned int* __restrict__ io,
                                                float* __restrict__ out,
                                                int* __restrict__ counts,
                                                float* __restrict__ lossp) {
    const int row = blockIdx.x;
    const int lane = threadIdx.x;

    float V1 = INFINITY, V2 = INFINITY;
    unsigned int I1 = 0xFFFFu, I2 = 0xFFFFu;
#pragma unroll
    for (int p = 0; p < NPOOL; ++p) {
        size_t o = (size_t)p * N_ROWS + row;
        float bv1 = v1[o], bv2 = v2[o];
        unsigned int ox = io[o];
        unsigned int bi1 = ox & 0xFFFFu, bi2 = ox >> 16;
        bool bf = (bv1 < V1) || (bv1 == V1 && bi1 < I1);
        float n1v = bf ? bv1 : V1; unsigned int n1i = bf ? bi1 : I1;
        float w1v = bf ? V1 : bv1; unsigned int w1i = bf ? I1 : bi1;
        bool cf = (bv2 < V2) || (bv2 == V2 && bi2 < I2);
        float c2v = cf ? bv2 : V2; unsigned int c2i = cf ? bi2 : I2;
        bool df = (c2v < w1v) || (c2v == w1v && c2i < w1i);
        V1 = n1v; I1 = n1i;
        V2 = df ? c2v : w1v; I2 = df ? c2i : w1i;
    }

    int c = (int)I1;
    if (V2 - V1 < MARGIN) {
        unsigned int cand[8];
#pragma unroll
        for (int p = 0; p < NPOOL; ++p) {
            unsigned int ox = io[(size_t)p * N_ROWS + row];
            cand[2 * p] = ox & 0xFFFFu;
            cand[2 * p + 1] = ox >> 16;
        }
        double xd[8];
#pragma unroll
        for (int kk = 0; kk < 8; ++kk)
            xd[kk] = (double)x[(size_t)row * DIM + lane + 64 * kk];
        double best = 1e300;
        unsigned int bi = 0xFFFFFFFFu;
#pragma unroll
        for (int t = 0; t < 8; ++t) {
            const float* e1 = emb + (size_t)cand[t] * DIM;
            double d = 0.0;
#pragma unroll
            for (int kk = 0; kk < 8; ++kk) {
                double df = xd[kk] - (double)e1[lane + 64 * kk];
                d = fma(df, df, d);
            }
#pragma unroll
            for (int m = 1; m <= 32; m <<= 1) d += __shfl_xor(d, m);
            if (d < best || (d == best && cand[t] < bi)) { best = d; bi = cand[t]; }
        }
        c = (int)bi;
    }

    const float4* xr4 = reinterpret_cast<const float4*>(x + (size_t)row * DIM);
    const float4* er4 = reinterpret_cast<const float4*>(emb + (size_t)c * DIM);
    float4* qo = reinterpret_cast<float4*>(out + (size_t)row * DIM);
    float lsum = 0.f;
#pragma unroll
    for (int k = 0; k < 2; ++k) {
        int idx = lane + 64 * k;
        float4 e = er4[idx];
        float4 xv = xr4[idx];
        qo[idx] = e;
        float dx = xv.x - e.x, dy = xv.y - e.y, dz = xv.z - e.z, dw = xv.w - e.w;
        lsum += dx * dx + dy * dy + dz * dz + dw * dw;
    }
#pragma unroll
    for (int off = 32; off > 0; off >>= 1) lsum += __shfl_down(lsum, off);
    if (lane == 0) {
        lossp[row] = lsum;
        atomicAdd(&counts[c], 1);
        out[Q_OFF + 2 + row] = (float)c;   // indices as float (d_out is f32)
    }
}

// ---------------------------------------------------------------------------
// Single block: fp64 loss sum + perplexity, write scalars.
// ---------------------------------------------------------------------------
__global__ __launch_bounds__(256) void vq_finalize(const float* __restrict__ lossp,
                                                   const int* __restrict__ counts,
                                                   float* __restrict__ out) {
    __shared__ double sred[8];
    const int tid = threadIdx.x;
    const int lane = tid & 63, wv = tid >> 6;
    double ls = 0.0, hs = 0.0;
    for (int r = tid; r < N_ROWS; r += 256) ls += (double)lossp[r];
    for (int cidx = tid; cidx < K_CODES; cidx += 256) {
        double p = (double)counts[cidx] * (1.0 / (double)N_ROWS);
        hs += p * log(p + 1e-10);
    }
#pragma unroll
    for (int off = 32; off > 0; off >>= 1) {
        ls += __shfl_down(ls, off);
        hs += __shfl_down(hs, off);
    }
    if (lane == 0) { sred[wv] = ls; sred[4 + wv] = hs; }
    __syncthreads();
    if (tid == 0) {
        double L = sred[0] + sred[1] + sred[2] + sred[3];
        double H = sred[4] + sred[5] + sred[6] + sred[7];
        out[Q_OFF]     = (float)(0.25 * L / (double)Q_OFF);   // commitment loss
        out[Q_OFF + 1] = (float)exp(-H);                      // perplexity
    }
}

// ---------------------------------------------------------------------------
extern "C" void kernel_launch(void* const* d_in, const int* in_sizes, int n_in,
                              void* d_out, int out_size, void* d_ws, size_t ws_size,
                              hipStream_t stream) {
    const float* x   = (const float*)d_in[0];
    const float* emb = (const float*)d_in[1];
    float* out = (float*)d_out;

    // workspace layout (u32 words)
    unsigned int* w = (unsigned int*)d_ws;
    float* esq          = (float*)(w);                       // 8192
    int*   counts       = (int*)(w + 8192);                  // 8192
    float* lossp        = (float*)(w + 16384);               // 32768
    float* v1           = (float*)(w + 49152);               // 4*32768
    float* v2           = (float*)(w + 180224);              // 4*32768
    unsigned int* io    = (unsigned int*)(w + 311296);       // 4*32768
    _Float16* x_hi      = (_Float16*)(w + 442368);           // 16.7M halves (32 MB)
    _Float16* x_lo      = (_Float16*)(w + 8830976);          // 32 MB
    _Float16* e_h       = (_Float16*)(w + 17219584);         // 8 MB
    const size_t need   = (size_t)19316736 * 4;              // ~77.3 MB

    const bool pk = ws_size >= need;

    vq_esq_init<<<(K_CODES * 64) / 256, 256, 0, stream>>>(emb, esq, counts);
    if (pk) {
        vq_pack_x<<<(N_ROWS * DIM / 8) / 256, 256, 0, stream>>>(
            (const float4*)x, (half8*)x_hi, (half8*)x_lo, N_ROWS * DIM / 8);
        vq_pack_e<<<(K_CODES * DIM / 8) / 256, 256, 0, stream>>>(
            (const float4*)emb, (half8*)e_h, K_CODES * DIM / 8);
    }

    dim3 grid(N_ROWS / 128, NSPLIT);
    if (pk)
        vq_argmin_f16<true><<<grid, 256, 0, stream>>>(
            x_hi, x_lo, e_h, nullptr, nullptr, esq, v1, v2, io);
    else
        vq_argmin_f16<false><<<grid, 256, 0, stream>>>(
            nullptr, nullptr, nullptr, x, emb, esq, v1, v2, io);

    vq_gather<<<N_ROWS, 64, 0, stream>>>(x, emb, v1, v2, io, out, counts, lossp);
    vq_finalize<<<1, 256, 0, stream>>>(lossp, counts, out);
}

// Round 5
// 636.408 us; speedup vs baseline: 5.9860x; 1.0073x over previous
//
#include <hip/hip_runtime.h>
#include <math.h>

#define N_ROWS 32768
#define K_CODES 8192
#define DIM 512
#define Q_OFF ((size_t)N_ROWS * DIM)   // 16777216 floats of quantized output

#define NSPLIT 2                        // codebook split across blockIdx.y
#define KSPL (K_CODES / NSPLIT)         // 4096 codes per block
#define NPOOL (NSPLIT * 2)              // 4 disjoint 2048-code pools per row
#define MARGIN_V 0.025f                 // v = (||e||^2 - 2 x.e)/2 units; ~50 sigma

typedef _Float16 half8 __attribute__((ext_vector_type(8)));
typedef float f32x4 __attribute__((ext_vector_type(4)));

#define GLOAD_LDS(src, dst)                                                        \
  __builtin_amdgcn_global_load_lds(                                                \
      (const __attribute__((address_space(1))) void*)(src),                        \
      (__attribute__((address_space(3))) void*)(dst), 16, 0, 0)

// ---------------------------------------------------------------------------
// Generic f32 -> f16 plane pack (16 floats per thread -> 2 half8)
// ---------------------------------------------------------------------------
__global__ __launch_bounds__(256) void vq_pack_f16(const float4* __restrict__ src,
                                                   half8* __restrict__ dst, int n8) {
    int i = blockIdx.x * 256 + threadIdx.x;
    if (i >= n8) return;
    float4 a = src[i * 2], b = src[i * 2 + 1];
    float v[8] = {a.x, a.y, a.z, a.w, b.x, b.y, b.z, b.w};
    half8 h;
#pragma unroll
    for (int k = 0; k < 8; ++k) h[k] = (_Float16)v[k];
    dst[i] = h;
}

// ---------------------------------------------------------------------------
// zero histogram counts + compute 0.5*||e||^2 per code (one wave/code)
// ---------------------------------------------------------------------------
__global__ __launch_bounds__(256) void vq_esq_init(const float* __restrict__ emb,
                                                   float* __restrict__ esqh,
                                                   int* __restrict__ counts) {
    int gid = blockIdx.x * 256 + threadIdx.x;
    if (gid < K_CODES) counts[gid] = 0;
    int code = gid >> 6;
    int lane = gid & 63;
    const float4* p = reinterpret_cast<const float4*>(emb + (size_t)code * DIM);
    float s = 0.f;
#pragma unroll
    for (int k = 0; k < 2; ++k) {
        float4 v = p[lane + 64 * k];
        s += v.x * v.x + v.y * v.y + v.z * v.z + v.w * v.w;
    }
#pragma unroll
    for (int off = 32; off > 0; off >>= 1) s += __shfl_down(s, off);
    if (lane == 0) esqh[code] = 0.5f * s;
}

// ---------------------------------------------------------------------------
// Fragment read: row-major [rows][32 halves] tile, 16B slots XOR-swizzled by
// (row&3).  Lane (lr,kg) reads row, k-group kg.
// ---------------------------------------------------------------------------
__device__ __forceinline__ half8 frag16(const _Float16* t, int row, int kg) {
    return *reinterpret_cast<const half8*>(t + row * 32 + ((kg ^ (row & 3)) << 3));
}

// ---------------------------------------------------------------------------
// MFMA argmin, single f16 plane.  Block tile 128 rows x 256 codes, 4 waves
// (wr 2 x wc 2), wave 64x128 via 4x8 frags of mfma_f32_16x16x32_f16, 1 pass.
// Triple-buffered LDS (24 KB/buf), depth-2 global_load_lds prefetch, counted
// s_waitcnt vmcnt(6) + raw s_barrier per K-step (never vmcnt(0) mid-loop).
// v = 0.5||e||^2 - x.e ; per-lane running top-2 -> shfl_xor tree at end.
// ---------------------------------------------------------------------------
__global__ __launch_bounds__(256, 2) void vq_argmin_f16p(
        const _Float16* __restrict__ xh, const _Float16* __restrict__ eh,
        const float* __restrict__ esqh,
        float* __restrict__ v1o, float* __restrict__ v2o,
        unsigned int* __restrict__ io) {
    __shared__ __align__(16) _Float16 sbuf[3][12288];   // per buf: A 4096 | B 8192 halves

    const int tid = threadIdx.x;
    const int lane = tid & 63;
    const int wid = tid >> 6;
    const int wr = wid >> 1, wc = wid & 1;
    const int lr = lane & 15, kg = lane >> 4;
    const int row0 = blockIdx.x * 128;
    const int csplit0 = blockIdx.y * KSPL;

    // staging: per-lane inverse-swizzled global source, wave-uniform LDS dest
    int offA[2], dstA[2], offB[4], dstB[4];
#pragma unroll
    for (int c = 0; c < 2; ++c) {
        int rA = wid * 32 + c * 16 + (lane >> 2);
        int sxA = (lane & 3) ^ (rA & 3);
        offA[c] = rA * DIM + sxA * 8;
        dstA[c] = (wid * 32 + c * 16) * 32;
    }
#pragma unroll
    for (int c = 0; c < 4; ++c) {
        int rB = wid * 64 + c * 16 + (lane >> 2);
        int sxB = (lane & 3) ^ (rB & 3);
        offB[c] = rB * DIM + sxB * 8;
        dstB[c] = 4096 + (wid * 64 + c * 16) * 32;
    }

    auto stage = [&](int b, int s) {   // s = flat K-step 0..NS-1
        int cc = s >> 4, ks = s & 15;
        const _Float16* a0 = xh + (size_t)row0 * DIM + ks * 32;
        const _Float16* b0 = eh + (size_t)(csplit0 + cc * 256) * DIM + ks * 32;
        _Float16* base = &sbuf[b][0];
#pragma unroll
        for (int c = 0; c < 2; ++c) GLOAD_LDS(a0 + offA[c], base + dstA[c]);
#pragma unroll
        for (int c = 0; c < 4; ++c) GLOAD_LDS(b0 + offB[c], base + dstB[c]);
    };

    float rv1[16], rv2[16];
    unsigned int ridx[16];
#pragma unroll
    for (int t = 0; t < 16; ++t) { rv1[t] = INFINITY; rv2[t] = INFINITY; ridx[t] = 0; }

    // preload esqh/2-values for cc=0
    float eq[8];
#pragma unroll
    for (int j = 0; j < 8; ++j) eq[j] = esqh[csplit0 + wc * 128 + j * 16 + lr];

    stage(0, 0);
    stage(1, 1);

    f32x4 acc[4][8];
    const int NS = (KSPL / 256) * 16;   // 256 K-steps
    int cur = 0;
    for (int s = 0; s < NS; ++s) {
        if (s == NS - 1) { asm volatile("s_waitcnt vmcnt(0)" ::: "memory"); }
        else             { asm volatile("s_waitcnt vmcnt(6)" ::: "memory"); }
        __builtin_amdgcn_s_barrier();
        __builtin_amdgcn_sched_barrier(0);

        if (s + 2 < NS) {
            int nb = cur + 2; if (nb >= 3) nb -= 3;
            stage(nb, s + 2);
        }

        if ((s & 15) == 0) {
#pragma unroll
            for (int i = 0; i < 4; ++i)
#pragma unroll
                for (int j = 0; j < 8; ++j) acc[i][j] = (f32x4)(0.f);
        }

        const _Float16* Ah = &sbuf[cur][0];
        const _Float16* Be = &sbuf[cur][4096];
        half8 a[4];
#pragma unroll
        for (int i = 0; i < 4; ++i)
            a[i] = frag16(Ah, wr * 64 + i * 16 + lr, kg);
#pragma unroll
        for (int j = 0; j < 8; ++j) {
            half8 b = frag16(Be, wc * 128 + j * 16 + lr, kg);
#pragma unroll
            for (int i = 0; i < 4; ++i)
                acc[i][j] = __builtin_amdgcn_mfma_f32_16x16x32_f16(a[i], b, acc[i][j], 0, 0, 0);
        }

        if ((s & 15) == 15) {
            int cc = s >> 4;
            const bool more = (cc + 1) < (KSPL / 256);
            float eqn[8];
            if (more) {
#pragma unroll
                for (int j = 0; j < 8; ++j)
                    eqn[j] = esqh[csplit0 + (cc + 1) * 256 + wc * 128 + j * 16 + lr];
            }
#pragma unroll
            for (int j = 0; j < 8; ++j) {
                int cg = csplit0 + cc * 256 + wc * 128 + j * 16 + lr;
#pragma unroll
                for (int i = 0; i < 4; ++i) {
#pragma unroll
                    for (int r = 0; r < 4; ++r) {
                        float v = eq[j] - acc[i][j][r];
                        int t = i * 4 + r;
                        if (v < rv1[t]) {
                            rv2[t] = rv1[t]; ridx[t] = (ridx[t] << 16) | (unsigned int)cg; rv1[t] = v;
                        } else if (v < rv2[t]) {
                            rv2[t] = v; ridx[t] = (ridx[t] & 0xFFFFu) | ((unsigned int)cg << 16);
                        }
                    }
                }
            }
            if (more) {
#pragma unroll
                for (int j = 0; j < 8; ++j) eq[j] = eqn[j];
            }
        }

        cur += 1; if (cur == 3) cur = 0;
    }

    // cross-lane top-2 merge within each 16-lane group (same rows, disjoint cols)
#pragma unroll
    for (int m = 1; m <= 8; m <<= 1) {
#pragma unroll
        for (int t = 0; t < 16; ++t) {
            float bv1 = __shfl_xor(rv1[t], m);
            float bv2 = __shfl_xor(rv2[t], m);
            unsigned int ox = (unsigned int)__shfl_xor((int)ridx[t], m);
            unsigned int ai1 = ridx[t] & 0xFFFFu, ai2 = ridx[t] >> 16;
            unsigned int bi1 = ox & 0xFFFFu, bi2 = ox >> 16;
            float av1 = rv1[t], av2 = rv2[t];
            bool bf = (bv1 < av1) || (bv1 == av1 && bi1 < ai1);
            float n1v = bf ? bv1 : av1; unsigned int n1i = bf ? bi1 : ai1;
            float w1v = bf ? av1 : bv1; unsigned int w1i = bf ? ai1 : bi1;
            bool cf = (bv2 < av2) || (bv2 == av2 && bi2 < ai2);
            float c2v = cf ? bv2 : av2; unsigned int c2i = cf ? bi2 : ai2;
            bool df = (c2v < w1v) || (c2v == w1v && c2i < w1i);
            float n2v = df ? c2v : w1v; unsigned int n2i = df ? c2i : w1i;
            rv1[t] = n1v; rv2[t] = n2v; ridx[t] = n1i | (n2i << 16);
        }
    }

    if (lr == 0) {
#pragma unroll
        for (int t = 0; t < 16; ++t) {
            int rl = wr * 64 + (t >> 2) * 16 + kg * 4 + (t & 3);
            size_t o = (size_t)(blockIdx.y * 2 + wc) * N_ROWS + row0 + rl;
            v1o[o] = rv1[t]; v2o[o] = rv2[t]; io[o] = ridx[t];
        }
    }
}

// ---------------------------------------------------------------------------
// Fallback (workspace too small): same math, reg-staged f32->f16 conversion,
// simple double-buffer + __syncthreads.  Correctness path only.
// ---------------------------------------------------------------------------
__global__ __launch_bounds__(256, 2) void vq_argmin_fb(
        const float* __restrict__ xf, const float* __restrict__ ef,
        const float* __restrict__ esqh,
        float* __restrict__ v1o, float* __restrict__ v2o,
        unsigned int* __restrict__ io) {
    __shared__ __align__(16) _Float16 sbuf[2][12288];

    const int tid = threadIdx.x;
    const int lane = tid & 63;
    const int wid = tid >> 6;
    const int wr = wid >> 1, wc = wid & 1;
    const int lr = lane & 15, kg = lane >> 4;
    const int row0 = blockIdx.x * 128;
    const int csplit0 = blockIdx.y * KSPL;

    auto stage = [&](int b, int s) {
        int cc = s >> 4, ks = s & 15;
        {
            const int r = tid >> 1;
            const int k0 = (tid & 1) * 16;
            const float4* xp = reinterpret_cast<const float4*>(
                xf + (size_t)(row0 + r) * DIM + ks * 32 + k0);
            float4 f0 = xp[0], f1 = xp[1], f2 = xp[2], f3 = xp[3];
            float v[16] = {f0.x, f0.y, f0.z, f0.w, f1.x, f1.y, f1.z, f1.w,
                           f2.x, f2.y, f2.z, f2.w, f3.x, f3.y, f3.z, f3.w};
            half8 h0, h1;
#pragma unroll
            for (int k = 0; k < 8; ++k) { h0[k] = (_Float16)v[k]; h1[k] = (_Float16)v[8 + k]; }
            int s0 = (k0 >> 3) ^ (r & 3);
            int s1 = ((k0 >> 3) + 1) ^ (r & 3);
            _Float16* Ah = &sbuf[b][0];
            *reinterpret_cast<half8*>(Ah + r * 32 + s0 * 8) = h0;
            *reinterpret_cast<half8*>(Ah + r * 32 + s1 * 8) = h1;
        }
        {
            const int r = tid;
            const float4* ep = reinterpret_cast<const float4*>(
                ef + (size_t)(csplit0 + cc * 256 + r) * DIM + ks * 32);
            _Float16* Be = &sbuf[b][4096];
#pragma unroll
            for (int q = 0; q < 4; ++q) {
                float4 g0 = ep[q * 2], g1 = ep[q * 2 + 1];
                half8 h;
                h[0] = (_Float16)g0.x; h[1] = (_Float16)g0.y;
                h[2] = (_Float16)g0.z; h[3] = (_Float16)g0.w;
                h[4] = (_Float16)g1.x; h[5] = (_Float16)g1.y;
                h[6] = (_Float16)g1.z; h[7] = (_Float16)g1.w;
                *reinterpret_cast<half8*>(Be + r * 32 + ((q ^ (r & 3)) << 3)) = h;
            }
        }
    };

    float rv1[16], rv2[16];
    unsigned int ridx[16];
#pragma unroll
    for (int t = 0; t < 16; ++t) { rv1[t] = INFINITY; rv2[t] = INFINITY; ridx[t] = 0; }

    f32x4 acc[4][8];
    const int NS = (KSPL / 256) * 16;
    int cur = 0;
    stage(0, 0);
    __syncthreads();
    for (int s = 0; s < NS; ++s) {
        if ((s & 15) == 0) {
#pragma unroll
            for (int i = 0; i < 4; ++i)
#pragma unroll
                for (int j = 0; j < 8; ++j) acc[i][j] = (f32x4)(0.f);
        }
        const _Float16* Ah = &sbuf[cur][0];
        const _Float16* Be = &sbuf[cur][4096];
        half8 a[4];
#pragma unroll
        for (int i = 0; i < 4; ++i) a[i] = frag16(Ah, wr * 64 + i * 16 + lr, kg);
#pragma unroll
        for (int j = 0; j < 8; ++j) {
            half8 b = frag16(Be, wc * 128 + j * 16 + lr, kg);
#pragma unroll
            for (int i = 0; i < 4; ++i)
                acc[i][j] = __builtin_amdgcn_mfma_f32_16x16x32_f16(a[i], b, acc[i][j], 0, 0, 0);
        }
        if (s + 1 < NS) {
            stage(cur ^ 1, s + 1);
        }
        if ((s & 15) == 15) {
            int cc = s >> 4;
#pragma unroll
            for (int j = 0; j < 8; ++j) {
                int cg = csplit0 + cc * 256 + wc * 128 + j * 16 + lr;
                float eqv = esqh[cg];
#pragma unroll
                for (int i = 0; i < 4; ++i) {
#pragma unroll
                    for (int r = 0; r < 4; ++r) {
                        float v = eqv - acc[i][j][r];
                        int t = i * 4 + r;
                        if (v < rv1[t]) {
                            rv2[t] = rv1[t]; ridx[t] = (ridx[t] << 16) | (unsigned int)cg; rv1[t] = v;
                        } else if (v < rv2[t]) {
                            rv2[t] = v; ridx[t] = (ridx[t] & 0xFFFFu) | ((unsigned int)cg << 16);
                        }
                    }
                }
            }
        }
        __syncthreads();
        cur ^= 1;
    }

#pragma unroll
    for (int m = 1; m <= 8; m <<= 1) {
#pragma unroll
        for (int t = 0; t < 16; ++t) {
            float bv1 = __shfl_xor(rv1[t], m);
            float bv2 = __shfl_xor(rv2[t], m);
            unsigned int ox = (unsigned int)__shfl_xor((int)ridx[t], m);
            unsigned int ai1 = ridx[t] & 0xFFFFu, ai2 = ridx[t] >> 16;
            unsigned int bi1 = ox & 0xFFFFu, bi2 = ox >> 16;
            float av1 = rv1[t], av2 = rv2[t];
            bool bf = (bv1 < av1) || (bv1 == av1 && bi1 < ai1);
            float n1v = bf ? bv1 : av1; unsigned int n1i = bf ? bi1 : ai1;
            float w1v = bf ? av1 : bv1; unsigned int w1i = bf ? ai1 : bi1;
            bool cf = (bv2 < av2) || (bv2 == av2 && bi2 < ai2);
            float c2v = cf ? bv2 : av2; unsigned int c2i = cf ? bi2 : ai2;
            bool df = (c2v < w1v) || (c2v == w1v && c2i < w1i);
            float n2v = df ? c2v : w1v; unsigned int n2i = df ? c2i : w1i;
            rv1[t] = n1v; rv2[t] = n2v; ridx[t] = n1i | (n2i << 16);
        }
    }
    if (lr == 0) {
#pragma unroll
        for (int t = 0; t < 16; ++t) {
            int rl = wr * 64 + (t >> 2) * 16 + kg * 4 + (t & 3);
            size_t o = (size_t)(blockIdx.y * 2 + wc) * N_ROWS + row0 + rl;
            v1o[o] = rv1[t]; v2o[o] = rv2[t]; io[o] = ridx[t];
        }
    }
}

// ---------------------------------------------------------------------------
// Per-row (one wave): merge 4 pool top-2s; if global gap < MARGIN_V, fp64
// re-score all 8 candidates; gather embedding row, loss partial, histogram.
// ---------------------------------------------------------------------------
__global__ __launch_bounds__(64) void vq_gather(const float* __restrict__ x,
                                                const float* __restrict__ emb,
                                                const float* __restrict__ v1,
                                                const float* __restrict__ v2,
                                                const unsigned int* __restrict__ io,
                                                float* __restrict__ out,
                                                int* __restrict__ counts,
                                                float* __restrict__ lossp) {
    const int row = blockIdx.x;
    const int lane = threadIdx.x;

    float V1 = INFINITY, V2 = INFINITY;
    unsigned int I1 = 0xFFFFu, I2 = 0xFFFFu;
#pragma unroll
    for (int p = 0; p < NPOOL; ++p) {
        size_t o = (size_t)p * N_ROWS + row;
        float bv1 = v1[o], bv2 = v2[o];
        unsigned int ox = io[o];
        unsigned int bi1 = ox & 0xFFFFu, bi2 = ox >> 16;
        bool bf = (bv1 < V1) || (bv1 == V1 && bi1 < I1);
        float n1v = bf ? bv1 : V1; unsigned int n1i = bf ? bi1 : I1;
        float w1v = bf ? V1 : bv1; unsigned int w1i = bf ? I1 : bi1;
        bool cf = (bv2 < V2) || (bv2 == V2 && bi2 < I2);
        float c2v = cf ? bv2 : V2; unsigned int c2i = cf ? bi2 : I2;
        bool df = (c2v < w1v) || (c2v == w1v && c2i < w1i);
        V1 = n1v; I1 = n1i;
        V2 = df ? c2v : w1v; I2 = df ? c2i : w1i;
    }

    int c = (int)I1;
    if (V2 - V1 < MARGIN_V) {
        unsigned int cand[8];
#pragma unroll
        for (int p = 0; p < NPOOL; ++p) {
            unsigned int ox = io[(size_t)p * N_ROWS + row];
            cand[2 * p] = ox & 0xFFFFu;
            cand[2 * p + 1] = ox >> 16;
        }
        double xd[8];
#pragma unroll
        for (int kk = 0; kk < 8; ++kk)
            xd[kk] = (double)x[(size_t)row * DIM + lane + 64 * kk];
        double best = 1e300;
        unsigned int bi = 0xFFFFFFFFu;
#pragma unroll
        for (int t = 0; t < 8; ++t) {
            const float* e1 = emb + (size_t)cand[t] * DIM;
            double d = 0.0;
#pragma unroll
            for (int kk = 0; kk < 8; ++kk) {
                double df = xd[kk] - (double)e1[lane + 64 * kk];
                d = fma(df, df, d);
            }
#pragma unroll
            for (int m = 1; m <= 32; m <<= 1) d += __shfl_xor(d, m);
            if (d < best || (d == best && cand[t] < bi)) { best = d; bi = cand[t]; }
        }
        c = (int)bi;
    }

    const float4* xr4 = reinterpret_cast<const float4*>(x + (size_t)row * DIM);
    const float4* er4 = reinterpret_cast<const float4*>(emb + (size_t)c * DIM);
    float4* qo = reinterpret_cast<float4*>(out + (size_t)row * DIM);
    float lsum = 0.f;
#pragma unroll
    for (int k = 0; k < 2; ++k) {
        int idx = lane + 64 * k;
        float4 e = er4[idx];
        float4 xv = xr4[idx];
        qo[idx] = e;
        float dx = xv.x - e.x, dy = xv.y - e.y, dz = xv.z - e.z, dw = xv.w - e.w;
        lsum += dx * dx + dy * dy + dz * dz + dw * dw;
    }
#pragma unroll
    for (int off = 32; off > 0; off >>= 1) lsum += __shfl_down(lsum, off);
    if (lane == 0) {
        lossp[row] = lsum;
        atomicAdd(&counts[c], 1);
        out[Q_OFF + 2 + row] = (float)c;   // indices as float (d_out is f32)
    }
}

// ---------------------------------------------------------------------------
// Single block: fp64 loss sum + perplexity, write scalars.
// ---------------------------------------------------------------------------
__global__ __launch_bounds__(256) void vq_finalize(const float* __restrict__ lossp,
                                                   const int* __restrict__ counts,
                                                   float* __restrict__ out) {
    __shared__ double sred[8];
    const int tid = threadIdx.x;
    const int lane = tid & 63, wv = tid >> 6;
    double ls = 0.0, hs = 0.0;
    for (int r = tid; r < N_ROWS; r += 256) ls += (double)lossp[r];
    for (int cidx = tid; cidx < K_CODES; cidx += 256) {
        double p = (double)counts[cidx] * (1.0 / (double)N_ROWS);
        hs += p * log(p + 1e-10);
    }
#pragma unroll
    for (int off = 32; off > 0; off >>= 1) {
        ls += __shfl_down(ls, off);
        hs += __shfl_down(hs, off);
    }
    if (lane == 0) { sred[wv] = ls; sred[4 + wv] = hs; }
    __syncthreads();
    if (tid == 0) {
        double L = sred[0] + sred[1] + sred[2] + sred[3];
        double H = sred[4] + sred[5] + sred[6] + sred[7];
        out[Q_OFF]     = (float)(0.25 * L / (double)Q_OFF);   // commitment loss
        out[Q_OFF + 1] = (float)exp(-H);                      // perplexity
    }
}

// ---------------------------------------------------------------------------
extern "C" void kernel_launch(void* const* d_in, const int* in_sizes, int n_in,
                              void* d_out, int out_size, void* d_ws, size_t ws_size,
                              hipStream_t stream) {
    const float* x   = (const float*)d_in[0];
    const float* emb = (const float*)d_in[1];
    float* out = (float*)d_out;

    // workspace layout (u32 words)
    unsigned int* w = (unsigned int*)d_ws;
    float* esqh         = (float*)(w);                       // 8192
    int*   counts       = (int*)(w + 8192);                  // 8192
    float* lossp        = (float*)(w + 16384);               // 32768
    float* v1           = (float*)(w + 49152);               // 4*32768
    float* v2           = (float*)(w + 180224);              // 4*32768
    unsigned int* io    = (unsigned int*)(w + 311296);       // 4*32768
    _Float16* x_h       = (_Float16*)(w + 442368);           // 16.7M halves (32 MB)
    _Float16* e_h       = (_Float16*)(w + 8830976);          // 4.2M halves (8 MB)
    const size_t need   = (size_t)10928128 * 4;              // ~43.7 MB

    const bool pk = ws_size >= need;

    vq_esq_init<<<(K_CODES * 64) / 256, 256, 0, stream>>>(emb, esqh, counts);
    if (pk) {
        vq_pack_f16<<<(N_ROWS * DIM / 8) / 256, 256, 0, stream>>>(
            (const float4*)x, (half8*)x_h, N_ROWS * DIM / 8);
        vq_pack_f16<<<(K_CODES * DIM / 8) / 256, 256, 0, stream>>>(
            (const float4*)emb, (half8*)e_h, K_CODES * DIM / 8);
    }

    dim3 grid(N_ROWS / 128, NSPLIT);
    if (pk)
        vq_argmin_f16p<<<grid, 256, 0, stream>>>(x_h, e_h, esqh, v1, v2, io);
    else
        vq_argmin_fb<<<grid, 256, 0, stream>>>(x, emb, esqh, v1, v2, io);

    vq_gather<<<N_ROWS, 64, 0, stream>>>(x, emb, v1, v2, io, out, counts, lossp);
    vq_finalize<<<1, 256, 0, stream>>>(lossp, counts, out);
}

// Round 6
// 456.969 us; speedup vs baseline: 8.3365x; 1.3927x over previous
//
#include <hip/hip_runtime.h>
#include <math.h>

#define N_ROWS 32768
#define K_CODES 8192
#define DIM 512
#define Q_OFF ((size_t)N_ROWS * DIM)   // 16777216 floats of quantized output

#define NSPLIT 2                        // codebook split across blockIdx.y
#define KSPL (K_CODES / NSPLIT)         // 4096 codes per block
#define NPOOL (NSPLIT * 2)              // 4 disjoint 2048-code pools per row
#define MARGIN_V 0.025f                 // v = d/2 - ||x||^2/2 units; ~23 sigma of f16 err

typedef _Float16 half8 __attribute__((ext_vector_type(8)));
typedef float f32x4 __attribute__((ext_vector_type(4)));

#define GLOAD_LDS(src, dst)                                                        \
  __builtin_amdgcn_global_load_lds(                                                \
      (const __attribute__((address_space(1))) void*)(src),                        \
      (__attribute__((address_space(3))) void*)(dst), 16, 0, 0)

// ---------------------------------------------------------------------------
// f32 -> f16 plane pack (16 floats per thread -> 2 half8)
// ---------------------------------------------------------------------------
__global__ __launch_bounds__(256) void vq_pack_f16(const float4* __restrict__ src,
                                                   half8* __restrict__ dst, int n8) {
    int i = blockIdx.x * 256 + threadIdx.x;
    if (i >= n8) return;
    float4 a = src[i * 2], b = src[i * 2 + 1];
    float v[8] = {a.x, a.y, a.z, a.w, b.x, b.y, b.z, b.w};
    half8 h;
#pragma unroll
    for (int k = 0; k < 8; ++k) h[k] = (_Float16)v[k];
    dst[i] = h;
}

// ---------------------------------------------------------------------------
// zero histogram counts + compute 0.5*||e||^2 per code (one wave/code)
// ---------------------------------------------------------------------------
__global__ __launch_bounds__(256) void vq_esq_init(const float* __restrict__ emb,
                                                   float* __restrict__ esqh,
                                                   int* __restrict__ counts) {
    int gid = blockIdx.x * 256 + threadIdx.x;
    if (gid < K_CODES) counts[gid] = 0;
    int code = gid >> 6;
    int lane = gid & 63;
    const float4* p = reinterpret_cast<const float4*>(emb + (size_t)code * DIM);
    float s = 0.f;
#pragma unroll
    for (int k = 0; k < 2; ++k) {
        float4 v = p[lane + 64 * k];
        s += v.x * v.x + v.y * v.y + v.z * v.z + v.w * v.w;
    }
#pragma unroll
    for (int off = 32; off > 0; off >>= 1) s += __shfl_down(s, off);
    if (lane == 0) esqh[code] = 0.5f * s;
}

// ---------------------------------------------------------------------------
// Fragment read, quad-buffer kernel: tile row-major [128 rows][32 halves],
// 16B slots XOR-swizzled by ((row>>2)&3)  (fixes 4-way quarter-wave conflicts
// of the old (row&3) swizzle).
// ---------------------------------------------------------------------------
__device__ __forceinline__ half8 fragq(const _Float16* t, int row, int kg) {
    return *reinterpret_cast<const half8*>(t + row * 32 + ((kg ^ ((row >> 2) & 3)) << 3));
}

// old-swizzle reader, used by fallback kernel only
__device__ __forceinline__ half8 frag16(const _Float16* t, int row, int kg) {
    return *reinterpret_cast<const half8*>(t + row * 32 + ((kg ^ (row & 3)) << 3));
}

// ---------------------------------------------------------------------------
// MFMA argmin, single f16 plane, quad-buffered pipeline.
// Block tile 128 rows x 128 codes, 4 waves (wr 2 x wc 2), wave 64x64 via
// 4x4 frags of mfma_f32_16x16x32_f16.  4 LDS buffers x 16 KB (A 8K | B 8K),
// depth-2 global_load_lds prefetch, counted s_waitcnt vmcnt(4) + raw
// s_barrier per K-step; buffer index = ks&3 (compile-time: inner loop fully
// unrolled, 16 steps/cc-tile).  Last cc-tile peeled (drain).
// v = 0.5||e||^2 - x.e ; per-lane running top-2 -> shfl_xor tree at end.
// ---------------------------------------------------------------------------
__global__ __launch_bounds__(256, 2) void vq_argmin_f16q(
        const _Float16* __restrict__ xh, const _Float16* __restrict__ eh,
        const float* __restrict__ esqh,
        float* __restrict__ v1o, float* __restrict__ v2o,
        unsigned int* __restrict__ io) {
    __shared__ __align__(16) _Float16 sbuf[4][8192];   // per buf: A 4096 | B 4096 halves

    const int tid = threadIdx.x;
    const int lane = tid & 63;
    const int wid = tid >> 6;
    const int wr = wid >> 1, wc = wid & 1;
    const int lr = lane & 15, kg = lane >> 4;
    const int row0 = blockIdx.x * 128;
    const int csplit0 = blockIdx.y * KSPL;

    // staging: per-lane inverse-swizzled global offset, wave-uniform LDS dest.
    // Wave wid, round c covers tile rows wid*32 + c*16 + (lane>>2), slot lane&3.
    int off[2], dstA[2], dstB[2];
#pragma unroll
    for (int c = 0; c < 2; ++c) {
        int r = wid * 32 + c * 16 + (lane >> 2);
        int sx = (lane & 3) ^ ((r >> 2) & 3);
        off[c] = r * DIM + sx * 8;
        dstA[c] = (wid * 32 + c * 16) * 32;
        dstB[c] = 4096 + dstA[c];
    }

    auto stage = [&](int b, int s) {   // s = flat K-step (cc*16 + ks)
        int cc = s >> 4, ks = s & 15;
        const _Float16* a0 = xh + (size_t)row0 * DIM + ks * 32;
        const _Float16* b0 = eh + (size_t)(csplit0 + cc * 128) * DIM + ks * 32;
        _Float16* base = &sbuf[b][0];
#pragma unroll
        for (int c = 0; c < 2; ++c) {
            GLOAD_LDS(a0 + off[c], base + dstA[c]);
            GLOAD_LDS(b0 + off[c], base + dstB[c]);
        }
    };

    auto compute = [&](int bq, f32x4 (&acc)[4][4]) {
        const _Float16* A = &sbuf[bq][0];
        const _Float16* B = &sbuf[bq][4096];
        half8 a[4], b[4];
#pragma unroll
        for (int i = 0; i < 4; ++i) a[i] = fragq(A, wr * 64 + i * 16 + lr, kg);
#pragma unroll
        for (int j = 0; j < 4; ++j) b[j] = fragq(B, wc * 64 + j * 16 + lr, kg);
#pragma unroll
        for (int j = 0; j < 4; ++j)
#pragma unroll
            for (int i = 0; i < 4; ++i)
                acc[i][j] = __builtin_amdgcn_mfma_f32_16x16x32_f16(a[i], b[j], acc[i][j], 0, 0, 0);
    };

    float rv1[16], rv2[16];
    unsigned int ridx[16];
#pragma unroll
    for (int t = 0; t < 16; ++t) { rv1[t] = INFINITY; rv2[t] = INFINITY; ridx[t] = 0; }

    auto fold = [&](int cc, f32x4 (&acc)[4][4]) {
#pragma unroll
        for (int j = 0; j < 4; ++j) {
            int cg = csplit0 + cc * 128 + wc * 64 + j * 16 + lr;
            float eqv = esqh[cg];
#pragma unroll
            for (int i = 0; i < 4; ++i) {
#pragma unroll
                for (int r = 0; r < 4; ++r) {
                    float v = eqv - acc[i][j][r];
                    int t = i * 4 + r;
                    if (v < rv1[t]) {
                        rv2[t] = rv1[t]; ridx[t] = (ridx[t] << 16) | (unsigned int)cg; rv1[t] = v;
                    } else if (v < rv2[t]) {
                        rv2[t] = v; ridx[t] = (ridx[t] & 0xFFFFu) | ((unsigned int)cg << 16);
                    }
                }
            }
        }
    };

    const int NCC = KSPL / 128;   // 32 cc-tiles, 16 K-steps each
    stage(0, 0);
    stage(1, 1);

    for (int cc = 0; cc < NCC - 1; ++cc) {
        f32x4 acc[4][4];
#pragma unroll
        for (int i = 0; i < 4; ++i)
#pragma unroll
            for (int j = 0; j < 4; ++j) acc[i][j] = (f32x4)(0.f);
#pragma unroll
        for (int ks = 0; ks < 16; ++ks) {
            asm volatile("s_waitcnt vmcnt(4)" ::: "memory");
            __builtin_amdgcn_s_barrier();
            stage((ks + 2) & 3, cc * 16 + ks + 2);
            compute(ks & 3, acc);
        }
        fold(cc, acc);
    }
    {   // peeled last cc-tile: finish staging (ks<14), drain at ks==15
        const int cc = NCC - 1;
        f32x4 acc[4][4];
#pragma unroll
        for (int i = 0; i < 4; ++i)
#pragma unroll
            for (int j = 0; j < 4; ++j) acc[i][j] = (f32x4)(0.f);
#pragma unroll
        for (int ks = 0; ks < 16; ++ks) {
            if (ks == 15) asm volatile("s_waitcnt vmcnt(0)" ::: "memory");
            else          asm volatile("s_waitcnt vmcnt(4)" ::: "memory");
            __builtin_amdgcn_s_barrier();
            if (ks < 14) stage((ks + 2) & 3, cc * 16 + ks + 2);
            compute(ks & 3, acc);
        }
        fold(cc, acc);
    }

    // cross-lane top-2 merge within each 16-lane group (same rows, disjoint cols)
#pragma unroll
    for (int m = 1; m <= 8; m <<= 1) {
#pragma unroll
        for (int t = 0; t < 16; ++t) {
            float bv1 = __shfl_xor(rv1[t], m);
            float bv2 = __shfl_xor(rv2[t], m);
            unsigned int ox = (unsigned int)__shfl_xor((int)ridx[t], m);
            unsigned int ai1 = ridx[t] & 0xFFFFu, ai2 = ridx[t] >> 16;
            unsigned int bi1 = ox & 0xFFFFu, bi2 = ox >> 16;
            float av1 = rv1[t], av2 = rv2[t];
            bool bf = (bv1 < av1) || (bv1 == av1 && bi1 < ai1);
            float n1v = bf ? bv1 : av1; unsigned int n1i = bf ? bi1 : ai1;
            float w1v = bf ? av1 : bv1; unsigned int w1i = bf ? ai1 : bi1;
            bool cf = (bv2 < av2) || (bv2 == av2 && bi2 < ai2);
            float c2v = cf ? bv2 : av2; unsigned int c2i = cf ? bi2 : ai2;
            bool df = (c2v < w1v) || (c2v == w1v && c2i < w1i);
            float n2v = df ? c2v : w1v; unsigned int n2i = df ? c2i : w1i;
            rv1[t] = n1v; rv2[t] = n2v; ridx[t] = n1i | (n2i << 16);
        }
    }

    if (lr == 0) {
#pragma unroll
        for (int t = 0; t < 16; ++t) {
            int rl = wr * 64 + (t >> 2) * 16 + kg * 4 + (t & 3);
            size_t o = (size_t)(blockIdx.y * 2 + wc) * N_ROWS + row0 + rl;
            v1o[o] = rv1[t]; v2o[o] = rv2[t]; io[o] = ridx[t];
        }
    }
}

// ---------------------------------------------------------------------------
// Fallback (workspace too small): reg-staged f32->f16, double-buffer,
// __syncthreads, 128x256 tile (old geometry/swizzle).  Correctness path only.
// ---------------------------------------------------------------------------
__global__ __launch_bounds__(256, 2) void vq_argmin_fb(
        const float* __restrict__ xf, const float* __restrict__ ef,
        const float* __restrict__ esqh,
        float* __restrict__ v1o, float* __restrict__ v2o,
        unsigned int* __restrict__ io) {
    __shared__ __align__(16) _Float16 sbuf[2][12288];

    const int tid = threadIdx.x;
    const int lane = tid & 63;
    const int wid = tid >> 6;
    const int wr = wid >> 1, wc = wid & 1;
    const int lr = lane & 15, kg = lane >> 4;
    const int row0 = blockIdx.x * 128;
    const int csplit0 = blockIdx.y * KSPL;

    auto stage = [&](int b, int s) {
        int cc = s >> 4, ks = s & 15;
        {
            const int r = tid >> 1;
            const int k0 = (tid & 1) * 16;
            const float4* xp = reinterpret_cast<const float4*>(
                xf + (size_t)(row0 + r) * DIM + ks * 32 + k0);
            float4 f0 = xp[0], f1 = xp[1], f2 = xp[2], f3 = xp[3];
            float v[16] = {f0.x, f0.y, f0.z, f0.w, f1.x, f1.y, f1.z, f1.w,
                           f2.x, f2.y, f2.z, f2.w, f3.x, f3.y, f3.z, f3.w};
            half8 h0, h1;
#pragma unroll
            for (int k = 0; k < 8; ++k) { h0[k] = (_Float16)v[k]; h1[k] = (_Float16)v[8 + k]; }
            int s0 = (k0 >> 3) ^ (r & 3);
            int s1 = ((k0 >> 3) + 1) ^ (r & 3);
            _Float16* Ah = &sbuf[b][0];
            *reinterpret_cast<half8*>(Ah + r * 32 + s0 * 8) = h0;
            *reinterpret_cast<half8*>(Ah + r * 32 + s1 * 8) = h1;
        }
        {
            const int r = tid;
            const float4* ep = reinterpret_cast<const float4*>(
                ef + (size_t)(csplit0 + cc * 256 + r) * DIM + ks * 32);
            _Float16* Be = &sbuf[b][4096];
#pragma unroll
            for (int q = 0; q < 4; ++q) {
                float4 g0 = ep[q * 2], g1 = ep[q * 2 + 1];
                half8 h;
                h[0] = (_Float16)g0.x; h[1] = (_Float16)g0.y;
                h[2] = (_Float16)g0.z; h[3] = (_Float16)g0.w;
                h[4] = (_Float16)g1.x; h[5] = (_Float16)g1.y;
                h[6] = (_Float16)g1.z; h[7] = (_Float16)g1.w;
                *reinterpret_cast<half8*>(Be + r * 32 + ((q ^ (r & 3)) << 3)) = h;
            }
        }
    };

    float rv1[16], rv2[16];
    unsigned int ridx[16];
#pragma unroll
    for (int t = 0; t < 16; ++t) { rv1[t] = INFINITY; rv2[t] = INFINITY; ridx[t] = 0; }

    f32x4 acc[4][8];
    const int NS = (KSPL / 256) * 16;
    int cur = 0;
    stage(0, 0);
    __syncthreads();
    for (int s = 0; s < NS; ++s) {
        if ((s & 15) == 0) {
#pragma unroll
            for (int i = 0; i < 4; ++i)
#pragma unroll
                for (int j = 0; j < 8; ++j) acc[i][j] = (f32x4)(0.f);
        }
        const _Float16* Ah = &sbuf[cur][0];
        const _Float16* Be = &sbuf[cur][4096];
        half8 a[4];
#pragma unroll
        for (int i = 0; i < 4; ++i) a[i] = frag16(Ah, wr * 64 + i * 16 + lr, kg);
#pragma unroll
        for (int j = 0; j < 8; ++j) {
            half8 b = frag16(Be, wc * 128 + j * 16 + lr, kg);
#pragma unroll
            for (int i = 0; i < 4; ++i)
                acc[i][j] = __builtin_amdgcn_mfma_f32_16x16x32_f16(a[i], b, acc[i][j], 0, 0, 0);
        }
        if (s + 1 < NS) stage(cur ^ 1, s + 1);
        if ((s & 15) == 15) {
            int cc = s >> 4;
#pragma unroll
            for (int j = 0; j < 8; ++j) {
                int cg = csplit0 + cc * 256 + wc * 128 + j * 16 + lr;
                float eqv = esqh[cg];
#pragma unroll
                for (int i = 0; i < 4; ++i) {
#pragma unroll
                    for (int r = 0; r < 4; ++r) {
                        float v = eqv - acc[i][j][r];
                        int t = i * 4 + r;
                        if (v < rv1[t]) {
                            rv2[t] = rv1[t]; ridx[t] = (ridx[t] << 16) | (unsigned int)cg; rv1[t] = v;
                        } else if (v < rv2[t]) {
                            rv2[t] = v; ridx[t] = (ridx[t] & 0xFFFFu) | ((unsigned int)cg << 16);
                        }
                    }
                }
            }
        }
        __syncthreads();
        cur ^= 1;
    }

#pragma unroll
    for (int m = 1; m <= 8; m <<= 1) {
#pragma unroll
        for (int t = 0; t < 16; ++t) {
            float bv1 = __shfl_xor(rv1[t], m);
            float bv2 = __shfl_xor(rv2[t], m);
            unsigned int ox = (unsigned int)__shfl_xor((int)ridx[t], m);
            unsigned int ai1 = ridx[t] & 0xFFFFu, ai2 = ridx[t] >> 16;
            unsigned int bi1 = ox & 0xFFFFu, bi2 = ox >> 16;
            float av1 = rv1[t], av2 = rv2[t];
            bool bf = (bv1 < av1) || (bv1 == av1 && bi1 < ai1);
            float n1v = bf ? bv1 : av1; unsigned int n1i = bf ? bi1 : ai1;
            float w1v = bf ? av1 : bv1; unsigned int w1i = bf ? ai1 : bi1;
            bool cf = (bv2 < av2) || (bv2 == av2 && bi2 < ai2);
            float c2v = cf ? bv2 : av2; unsigned int c2i = cf ? bi2 : ai2;
            bool df = (c2v < w1v) || (c2v == w1v && c2i < w1i);
            float n2v = df ? c2v : w1v; unsigned int n2i = df ? c2i : w1i;
            rv1[t] = n1v; rv2[t] = n2v; ridx[t] = n1i | (n2i << 16);
        }
    }
    if (lr == 0) {
#pragma unroll
        for (int t = 0; t < 16; ++t) {
            int rl = wr * 64 + (t >> 2) * 16 + kg * 4 + (t & 3);
            size_t o = (size_t)(blockIdx.y * 2 + wc) * N_ROWS + row0 + rl;
            v1o[o] = rv1[t]; v2o[o] = rv2[t]; io[o] = ridx[t];
        }
    }
}

// ---------------------------------------------------------------------------
// Per-row (one wave): merge 4 pool top-2s; if global gap < MARGIN_V, fp64
// re-score all 8 candidates; gather embedding row, loss partial, histogram.
// ---------------------------------------------------------------------------
__global__ __launch_bounds__(64) void vq_gather(const float* __restrict__ x,
                                                const float* __restrict__ emb,
                                                const float* __restrict__ v1,
                                                const float* __restrict__ v2,
                                                const unsigned int* __restrict__ io,
                                                float* __restrict__ out,
                                                int* __restrict__ counts,
                                                float* __restrict__ lossp) {
    const int row = blockIdx.x;
    const int lane = threadIdx.x;

    float V1 = INFINITY, V2 = INFINITY;
    unsigned int I1 = 0xFFFFu, I2 = 0xFFFFu;
#pragma unroll
    for (int p = 0; p < NPOOL; ++p) {
        size_t o = (size_t)p * N_ROWS + row;
        float bv1 = v1[o], bv2 = v2[o];
        unsigned int ox = io[o];
        unsigned int bi1 = ox & 0xFFFFu, bi2 = ox >> 16;
        bool bf = (bv1 < V1) || (bv1 == V1 && bi1 < I1);
        float n1v = bf ? bv1 : V1; unsigned int n1i = bf ? bi1 : I1;
        float w1v = bf ? V1 : bv1; unsigned int w1i = bf ? I1 : bi1;
        bool cf = (bv2 < V2) || (bv2 == V2 && bi2 < I2);
        float c2v = cf ? bv2 : V2; unsigned int c2i = cf ? bi2 : I2;
        bool df = (c2v < w1v) || (c2v == w1v && c2i < w1i);
        V1 = n1v; I1 = n1i;
        V2 = df ? c2v : w1v; I2 = df ? c2i : w1i;
    }

    int c = (int)I1;
    if (V2 - V1 < MARGIN_V) {
        unsigned int cand[8];
#pragma unroll
        for (int p = 0; p < NPOOL; ++p) {
            unsigned int ox = io[(size_t)p * N_ROWS + row];
            cand[2 * p] = ox & 0xFFFFu;
            cand[2 * p + 1] = ox >> 16;
        }
        double xd[8];
#pragma unroll
        for (int kk = 0; kk < 8; ++kk)
            xd[kk] = (double)x[(size_t)row * DIM + lane + 64 * kk];
        double best = 1e300;
        unsigned int bi = 0xFFFFFFFFu;
#pragma unroll
        for (int t = 0; t < 8; ++t) {
            const float* e1 = emb + (size_t)cand[t] * DIM;
            double d = 0.0;
#pragma unroll
            for (int kk = 0; kk < 8; ++kk) {
                double df = xd[kk] - (double)e1[lane + 64 * kk];
                d = fma(df, df, d);
            }
#pragma unroll
            for (int m = 1; m <= 32; m <<= 1) d += __shfl_xor(d, m);
            if (d < best || (d == best && cand[t] < bi)) { best = d; bi = cand[t]; }
        }
        c = (int)bi;
    }

    const float4* xr4 = reinterpret_cast<const float4*>(x + (size_t)row * DIM);
    const float4* er4 = reinterpret_cast<const float4*>(emb + (size_t)c * DIM);
    float4* qo = reinterpret_cast<float4*>(out + (size_t)row * DIM);
    float lsum = 0.f;
#pragma unroll
    for (int k = 0; k < 2; ++k) {
        int idx = lane + 64 * k;
        float4 e = er4[idx];
        float4 xv = xr4[idx];
        qo[idx] = e;
        float dx = xv.x - e.x, dy = xv.y - e.y, dz = xv.z - e.z, dw = xv.w - e.w;
        lsum += dx * dx + dy * dy + dz * dz + dw * dw;
    }
#pragma unroll
    for (int off = 32; off > 0; off >>= 1) lsum += __shfl_down(lsum, off);
    if (lane == 0) {
        lossp[row] = lsum;
        atomicAdd(&counts[c], 1);
        out[Q_OFF + 2 + row] = (float)c;   // indices as float (d_out is f32)
    }
}

// ---------------------------------------------------------------------------
// Single block: fp64 loss sum + perplexity, write scalars.
// ---------------------------------------------------------------------------
__global__ __launch_bounds__(256) void vq_finalize(const float* __restrict__ lossp,
                                                   const int* __restrict__ counts,
                                                   float* __restrict__ out) {
    __shared__ double sred[8];
    const int tid = threadIdx.x;
    const int lane = tid & 63, wv = tid >> 6;
    double ls = 0.0, hs = 0.0;
    for (int r = tid; r < N_ROWS; r += 256) ls += (double)lossp[r];
    for (int cidx = tid; cidx < K_CODES; cidx += 256) {
        double p = (double)counts[cidx] * (1.0 / (double)N_ROWS);
        hs += p * log(p + 1e-10);
    }
#pragma unroll
    for (int off = 32; off > 0; off >>= 1) {
        ls += __shfl_down(ls, off);
        hs += __shfl_down(hs, off);
    }
    if (lane == 0) { sred[wv] = ls; sred[4 + wv] = hs; }
    __syncthreads();
    if (tid == 0) {
        double L = sred[0] + sred[1] + sred[2] + sred[3];
        double H = sred[4] + sred[5] + sred[6] + sred[7];
        out[Q_OFF]     = (float)(0.25 * L / (double)Q_OFF);   // commitment loss
        out[Q_OFF + 1] = (float)exp(-H);                      // perplexity
    }
}

// ---------------------------------------------------------------------------
extern "C" void kernel_launch(void* const* d_in, const int* in_sizes, int n_in,
                              void* d_out, int out_size, void* d_ws, size_t ws_size,
                              hipStream_t stream) {
    const float* x   = (const float*)d_in[0];
    const float* emb = (const float*)d_in[1];
    float* out = (float*)d_out;

    // workspace layout (u32 words)
    unsigned int* w = (unsigned int*)d_ws;
    float* esqh         = (float*)(w);                       // 8192
    int*   counts       = (int*)(w + 8192);                  // 8192
    float* lossp        = (float*)(w + 16384);               // 32768
    float* v1           = (float*)(w + 49152);               // 4*32768
    float* v2           = (float*)(w + 180224);              // 4*32768
    unsigned int* io    = (unsigned int*)(w + 311296);       // 4*32768
    _Float16* x_h       = (_Float16*)(w + 442368);           // 16.7M halves (32 MB)
    _Float16* e_h       = (_Float16*)(w + 8830976);          // 4.2M halves (8 MB)
    const size_t need   = (size_t)10928128 * 4;              // ~43.7 MB

    const bool pk = ws_size >= need;

    vq_esq_init<<<(K_CODES * 64) / 256, 256, 0, stream>>>(emb, esqh, counts);
    if (pk) {
        vq_pack_f16<<<(N_ROWS * DIM / 8) / 256, 256, 0, stream>>>(
            (const float4*)x, (half8*)x_h, N_ROWS * DIM / 8);
        vq_pack_f16<<<(K_CODES * DIM / 8) / 256, 256, 0, stream>>>(
            (const float4*)emb, (half8*)e_h, K_CODES * DIM / 8);
    }

    dim3 grid(N_ROWS / 128, NSPLIT);
    if (pk)
        vq_argmin_f16q<<<grid, 256, 0, stream>>>(x_h, e_h, esqh, v1, v2, io);
    else
        vq_argmin_fb<<<grid, 256, 0, stream>>>(x, emb, esqh, v1, v2, io);

    vq_gather<<<N_ROWS, 64, 0, stream>>>(x, emb, v1, v2, io, out, counts, lossp);
    vq_finalize<<<1, 256, 0, stream>>>(lossp, counts, out);
}